// Round 1
// baseline (2831.943 us; speedup 1.0000x reference)
//
#include <hip/hip_runtime.h>
#include <math.h>

#define N_NODES 50000
#define FIN 512
#define H1 8
#define C1 16
#define D1 128   // H1*C1
#define D2 64

__device__ __forceinline__ void atomAddF(float* p, float v) {
    // native global_atomic_add_f32 on gfx950 (coarse-grained d_ws memory)
    unsafeAtomicAdd(p, v);
}

// ---------------- init: seed accumulators with bias, zero segment sums ----
__global__ __launch_bounds__(256) void k_init(float* __restrict__ out1,
                                              float* __restrict__ out2,
                                              float* __restrict__ s1,
                                              float* __restrict__ s2,
                                              const float* __restrict__ b1,
                                              const float* __restrict__ b2) {
    int i = blockIdx.x * 256 + threadIdx.x;
    if (i < N_NODES * D1) out1[i] = b1[i & (D1 - 1)];
    if (i < N_NODES * D2) out2[i] = b2[i & (D2 - 1)];
    if (i < N_NODES * H1) s1[i] = 0.f;
    if (i < N_NODES)      s2[i] = 0.f;
}

// ---------------- GEMM1: h1[50000,128] = x[50000,512] @ W1[512,128] -------
__global__ __launch_bounds__(256) void k_gemm1(const float* __restrict__ x,
                                               const float* __restrict__ W1,
                                               float* __restrict__ h1) {
    __shared__ float xs[16][FIN];
    const int t = threadIdx.x;
    const int n0 = blockIdx.x * 16;           // 3125 blocks exactly
    // stage 16 rows of x (32 KiB) coalesced
    const float4* xv = (const float4*)(x + (size_t)n0 * FIN);
    float4* xsv = (float4*)&xs[0][0];
    #pragma unroll
    for (int i = 0; i < 8; ++i) xsv[t + i * 256] = xv[t + i * 256];
    __syncthreads();

    const int c4 = t & 31;                    // 4-col group
    const int rp = t >> 5;                    // rows 2rp, 2rp+1
    float4 acc0 = {0,0,0,0}, acc1 = {0,0,0,0};
    const float* xr0 = xs[rp * 2];
    const float* xr1 = xs[rp * 2 + 1];
    const float4* Wv = (const float4*)W1 + c4;
    #pragma unroll 4
    for (int k = 0; k < FIN; ++k) {
        float4 w = Wv[(size_t)k * 32];
        float a = xr0[k], b = xr1[k];
        acc0.x += a * w.x; acc0.y += a * w.y; acc0.z += a * w.z; acc0.w += a * w.w;
        acc1.x += b * w.x; acc1.y += b * w.y; acc1.z += b * w.z; acc1.w += b * w.w;
    }
    size_t o0 = (size_t)(n0 + rp * 2) * D1 + c4 * 4;
    *(float4*)(h1 + o0) = acc0;
    *(float4*)(h1 + o0 + D1) = acc1;
}

// ---------------- attention dots layer 1: as1/ad1 [50000,8] ---------------
__global__ __launch_bounds__(256) void k_att1(const float* __restrict__ h1,
                                              const float* __restrict__ asrc,
                                              const float* __restrict__ adst,
                                              float* __restrict__ as1,
                                              float* __restrict__ ad1) {
    int idx = blockIdx.x * 256 + threadIdx.x;     // n*8+h
    if (idx >= N_NODES * H1) return;
    int h = idx & 7;
    const float4* hv = (const float4*)(h1 + (size_t)idx * 16); // n*128+h*16
    const float4* av = (const float4*)(asrc + h * 16);
    const float4* dv = (const float4*)(adst + h * 16);
    float ss = 0.f, sd = 0.f;
    #pragma unroll
    for (int i = 0; i < 4; ++i) {
        float4 hh = hv[i], aa = av[i], dd = dv[i];
        ss += hh.x*aa.x + hh.y*aa.y + hh.z*aa.z + hh.w*aa.w;
        sd += hh.x*dd.x + hh.y*dd.y + hh.z*dd.z + hh.w*dd.w;
    }
    as1[idx] = ss; ad1[idx] = sd;
}

// ---------------- edge pass 1a: ee = exp(leaky(as[s]+ad[d])), seg-sum -----
__global__ __launch_bounds__(256) void k_edge1a(const int* __restrict__ ei, int E,
                                                const float* __restrict__ as1,
                                                const float* __restrict__ ad1,
                                                float* __restrict__ ee1,
                                                float* __restrict__ s1) {
    int e = blockIdx.x * 256 + threadIdx.x;
    int ET = E + N_NODES;
    if (e >= ET) return;
    int s = (e < E) ? ei[e] : (e - E);
    int d = (e < E) ? ei[E + e] : (e - E);
    const float4* av = (const float4*)(as1 + (size_t)s * 8);
    const float4* dv = (const float4*)(ad1 + (size_t)d * 8);
    float4 a0 = av[0], a1 = av[1], b0 = dv[0], b1 = dv[1];
    float v[8] = {a0.x + b0.x, a0.y + b0.y, a0.z + b0.z, a0.w + b0.w,
                  a1.x + b1.x, a1.y + b1.y, a1.z + b1.z, a1.w + b1.w};
    float ee[8];
    #pragma unroll
    for (int h = 0; h < 8; ++h) {
        float u = v[h];
        u = (u > 0.f) ? u : 0.2f * u;          // leaky_relu 0.2
        ee[h] = __expf(u);                     // no max-shift needed (|u|<~14)
        atomAddF(&s1[(size_t)d * 8 + h], ee[h]);
    }
    float4* eo = (float4*)(ee1 + (size_t)e * 8);
    eo[0] = make_float4(ee[0], ee[1], ee[2], ee[3]);
    eo[1] = make_float4(ee[4], ee[5], ee[6], ee[7]);
}

// ---------------- edge pass 1b: out1[d] += h1[s] * alpha  (32 lanes/edge) -
__global__ __launch_bounds__(256) void k_edge1b(const int* __restrict__ ei, int E,
                                                const float* __restrict__ ee1,
                                                const float* __restrict__ s1,
                                                const float* __restrict__ h1,
                                                float* __restrict__ out1) {
    int gid = blockIdx.x * 256 + threadIdx.x;
    int lane = gid & 31;
    int e = gid >> 5;
    int ET = E + N_NODES;
    if (e >= ET) return;
    int s = (e < E) ? ei[e] : (e - E);
    int d = (e < E) ? ei[E + e] : (e - E);
    int h = lane >> 2;
    float alpha = ee1[(size_t)e * 8 + h] / (s1[(size_t)d * 8 + h] + 1e-16f);
    float4 hv = *(const float4*)(h1 + (size_t)s * D1 + lane * 4);
    float* op = out1 + (size_t)d * D1 + lane * 4;
    atomAddF(op + 0, hv.x * alpha);
    atomAddF(op + 1, hv.y * alpha);
    atomAddF(op + 2, hv.z * alpha);
    atomAddF(op + 3, hv.w * alpha);
}

// ------- GEMM2 (+ReLU on load) + attention dots layer 2 -------------------
__global__ __launch_bounds__(256) void k_gemm2(const float* __restrict__ out1,
                                               const float* __restrict__ W2,
                                               const float* __restrict__ av2,
                                               const float* __restrict__ dv2,
                                               float* __restrict__ h2,
                                               float* __restrict__ as2,
                                               float* __restrict__ ad2) {
    __shared__ float rs[4 * D1];
    const int t = threadIdx.x;
    const int n0 = blockIdx.x * 4;            // 12500 blocks exactly
    #pragma unroll
    for (int i = t; i < 4 * D1; i += 256)
        rs[i] = fmaxf(out1[(size_t)n0 * D1 + i], 0.f);   // fused ReLU
    __syncthreads();
    const int w = t >> 6;                     // wave = row
    const int c = t & 63;
    const int n = n0 + w;
    const float* r = rs + w * D1;
    float acc = 0.f;
    #pragma unroll 8
    for (int k = 0; k < D1; ++k) acc += r[k] * W2[(size_t)k * D2 + c];
    h2[(size_t)n * D2 + c] = acc;
    float ps = acc * av2[c];
    float pd = acc * dv2[c];
    #pragma unroll
    for (int m = 32; m; m >>= 1) { ps += __shfl_xor(ps, m, 64); pd += __shfl_xor(pd, m, 64); }
    if (c == 0) { as2[n] = ps; ad2[n] = pd; }
}

// ---------------- edge pass 2a ------------------------------------------
__global__ __launch_bounds__(256) void k_edge2a(const int* __restrict__ ei, int E,
                                                const float* __restrict__ as2,
                                                const float* __restrict__ ad2,
                                                float* __restrict__ ee2,
                                                float* __restrict__ s2) {
    int e = blockIdx.x * 256 + threadIdx.x;
    int ET = E + N_NODES;
    if (e >= ET) return;
    int s = (e < E) ? ei[e] : (e - E);
    int d = (e < E) ? ei[E + e] : (e - E);
    float u = as2[s] + ad2[d];
    u = (u > 0.f) ? u : 0.2f * u;
    float ee = __expf(u);
    ee2[e] = ee;
    atomAddF(&s2[d], ee);
}

// ---------------- edge pass 2b: out2[d] += h2[s]*alpha (16 lanes/edge) ----
__global__ __launch_bounds__(256) void k_edge2b(const int* __restrict__ ei, int E,
                                                const float* __restrict__ ee2,
                                                const float* __restrict__ s2,
                                                const float* __restrict__ h2,
                                                float* __restrict__ out2) {
    int gid = blockIdx.x * 256 + threadIdx.x;
    int lane = gid & 15;
    int e = gid >> 4;
    int ET = E + N_NODES;
    if (e >= ET) return;
    int s = (e < E) ? ei[e] : (e - E);
    int d = (e < E) ? ei[E + e] : (e - E);
    float alpha = ee2[e] / (s2[d] + 1e-16f);
    float4 hv = *(const float4*)(h2 + (size_t)s * D2 + lane * 4);
    float* op = out2 + (size_t)d * D2 + lane * 4;
    atomAddF(op + 0, hv.x * alpha);
    atomAddF(op + 1, hv.y * alpha);
    atomAddF(op + 2, hv.z * alpha);
    atomAddF(op + 3, hv.w * alpha);
}

// ---------------- log_softmax over 64 classes, wave per row ---------------
__global__ __launch_bounds__(256) void k_lsm(const float* __restrict__ out2,
                                             float* __restrict__ out) {
    const int t = threadIdx.x;
    const int n = blockIdx.x * 4 + (t >> 6);
    const int c = t & 63;
    float v = out2[(size_t)n * D2 + c];
    float m = v;
    #pragma unroll
    for (int mask = 32; mask; mask >>= 1) m = fmaxf(m, __shfl_xor(m, mask, 64));
    float ex = __expf(v - m);
    #pragma unroll
    for (int mask = 32; mask; mask >>= 1) ex += __shfl_xor(ex, mask, 64);
    out[(size_t)n * D2 + c] = v - m - __logf(ex);
}

extern "C" void kernel_launch(void* const* d_in, const int* in_sizes, int n_in,
                              void* d_out, int out_size, void* d_ws, size_t ws_size,
                              hipStream_t stream) {
    const float* x     = (const float*)d_in[0];
    const int*   ei    = (const int*)d_in[1];
    const float* W1    = (const float*)d_in[2];
    const float* asrc1 = (const float*)d_in[3];
    const float* adst1 = (const float*)d_in[4];
    const float* b1    = (const float*)d_in[5];
    const float* W2    = (const float*)d_in[6];
    const float* asrc2 = (const float*)d_in[7];
    const float* adst2 = (const float*)d_in[8];
    const float* b2    = (const float*)d_in[9];

    const int E  = in_sizes[1] / 2;   // 800000
    const int ET = E + N_NODES;       // 850000

    float* ws  = (float*)d_ws;
    float* h1   = ws;                                  // N*128
    float* out1 = h1   + (size_t)N_NODES * D1;         // N*128
    float* as1  = out1 + (size_t)N_NODES * D1;         // N*8
    float* ad1  = as1  + (size_t)N_NODES * H1;         // N*8
    float* s1   = ad1  + (size_t)N_NODES * H1;         // N*8
    float* ee1  = s1   + (size_t)N_NODES * H1;         // ET*8
    float* h2   = ee1  + (size_t)ET * H1;              // N*64
    float* out2 = h2   + (size_t)N_NODES * D2;         // N*64
    float* as2  = out2 + (size_t)N_NODES * D2;         // N
    float* ad2  = as2  + N_NODES;                      // N
    float* s2   = ad2  + N_NODES;                      // N
    float* ee2  = s2   + N_NODES;                      // ET

    k_init  <<<(N_NODES * D1 + 255) / 256, 256, 0, stream>>>(out1, out2, s1, s2, b1, b2);
    k_gemm1 <<<N_NODES / 16, 256, 0, stream>>>(x, W1, h1);
    k_att1  <<<(N_NODES * H1 + 255) / 256, 256, 0, stream>>>(h1, asrc1, adst1, as1, ad1);
    k_edge1a<<<(ET + 255) / 256, 256, 0, stream>>>(ei, E, as1, ad1, ee1, s1);
    k_edge1b<<<(ET * 32 + 255) / 256, 256, 0, stream>>>(ei, E, ee1, s1, h1, out1);
    k_gemm2 <<<N_NODES / 4, 256, 0, stream>>>(out1, W2, asrc2, adst2, h2, as2, ad2);
    k_edge2a<<<(ET + 255) / 256, 256, 0, stream>>>(ei, E, as2, ad2, ee2, s2);
    k_edge2b<<<(ET * 16 + 255) / 256, 256, 0, stream>>>(ei, E, ee2, s2, h2, out2);
    k_lsm   <<<N_NODES / 4, 256, 0, stream>>>(out2, (float*)d_out);
}

// Round 2
// 544.690 us; speedup vs baseline: 5.1992x; 5.1992x over previous
//
#include <hip/hip_runtime.h>
#include <math.h>

#define N_NODES 50000
#define FIN 512
#define H1 8
#define D1 128   // H1*C1
#define D2 64
#define NSCB ((N_NODES + 1023) >> 10)   // 49 scan blocks

// ---------------- zero histogram counters --------------------------------
__global__ __launch_bounds__(256) void k_zero(int* __restrict__ cnt, int* __restrict__ fill) {
    int i = blockIdx.x * 256 + threadIdx.x;
    if (i < N_NODES) { cnt[i] = 0; fill[i] = 0; }
}

// ---------------- histogram of dst ---------------------------------------
__global__ __launch_bounds__(256) void k_hist(const int* __restrict__ ei, int E,
                                              int* __restrict__ cnt) {
    int e = blockIdx.x * 256 + threadIdx.x;
    int ET = E + N_NODES;
    if (e >= ET) return;
    int d = (e < E) ? ei[E + e] : (e - E);
    atomicAdd(&cnt[d], 1);
}

// ---------------- scan stage 1: per-block exclusive scan of cnt ----------
__global__ __launch_bounds__(256) void k_scan1(const int* __restrict__ cnt,
                                               int* __restrict__ basep,
                                               int* __restrict__ aux) {
    __shared__ int lds[256];
    int t = threadIdx.x, b = blockIdx.x;
    int g = b * 1024 + t * 4;
    int v0 = (g + 0 < N_NODES) ? cnt[g + 0] : 0;
    int v1 = (g + 1 < N_NODES) ? cnt[g + 1] : 0;
    int v2 = (g + 2 < N_NODES) ? cnt[g + 2] : 0;
    int v3 = (g + 3 < N_NODES) ? cnt[g + 3] : 0;
    int tsum = v0 + v1 + v2 + v3;
    lds[t] = tsum; __syncthreads();
    for (int off = 1; off < 256; off <<= 1) {
        int add = (t >= off) ? lds[t - off] : 0;
        __syncthreads();
        lds[t] += add;
        __syncthreads();
    }
    int excl = lds[t] - tsum;
    if (g + 0 < N_NODES) basep[g + 0] = excl;
    if (g + 1 < N_NODES) basep[g + 1] = excl + v0;
    if (g + 2 < N_NODES) basep[g + 2] = excl + v0 + v1;
    if (g + 3 < N_NODES) basep[g + 3] = excl + v0 + v1 + v2;
    if (t == 255) aux[b] = lds[255];
}

// ---------------- scan stage 2: scan the 49 block sums (one wave) --------
__global__ __launch_bounds__(64) void k_scan2(const int* __restrict__ aux,
                                              int* __restrict__ auxs) {
    int t = threadIdx.x;
    int v = (t < NSCB) ? aux[t] : 0;
    int orig = v;
    for (int off = 1; off < 64; off <<= 1) {
        int x = __shfl_up(v, off, 64);
        if (t >= off) v += x;
    }
    auxs[t] = v - orig;
}

// ---------------- scan stage 3: add block offsets ------------------------
__global__ __launch_bounds__(256) void k_scan3(int* __restrict__ basep,
                                               const int* __restrict__ auxs, int ET) {
    int i = blockIdx.x * 256 + threadIdx.x;
    if (i < N_NODES) basep[i] += auxs[i >> 10];
    if (i == 0) basep[N_NODES] = ET;
}

// ---------------- scatter edges into dst-sorted order --------------------
__global__ __launch_bounds__(256) void k_scatter(const int* __restrict__ ei, int E,
                                                 const int* __restrict__ basep,
                                                 int* __restrict__ fill,
                                                 int* __restrict__ srcs) {
    int e = blockIdx.x * 256 + threadIdx.x;
    int ET = E + N_NODES;
    if (e >= ET) return;
    int s = (e < E) ? ei[e] : (e - E);
    int d = (e < E) ? ei[E + e] : (e - E);
    int pos = basep[d] + atomicAdd(&fill[d], 1);
    srcs[pos] = s;
}

// ---------------- GEMM1: h1[50000,128] = x[50000,512] @ W1[512,128] -------
__global__ __launch_bounds__(256) void k_gemm1(const float* __restrict__ x,
                                               const float* __restrict__ W1,
                                               float* __restrict__ h1) {
    __shared__ float xs[16][FIN];
    const int t = threadIdx.x;
    const int n0 = blockIdx.x * 16;           // 3125 blocks exactly
    const float4* xv = (const float4*)(x + (size_t)n0 * FIN);
    float4* xsv = (float4*)&xs[0][0];
    #pragma unroll
    for (int i = 0; i < 8; ++i) xsv[t + i * 256] = xv[t + i * 256];
    __syncthreads();

    const int c4 = t & 31;
    const int rp = t >> 5;
    float4 acc0 = {0,0,0,0}, acc1 = {0,0,0,0};
    const float* xr0 = xs[rp * 2];
    const float* xr1 = xs[rp * 2 + 1];
    const float4* Wv = (const float4*)W1 + c4;
    #pragma unroll 4
    for (int k = 0; k < FIN; ++k) {
        float4 w = Wv[(size_t)k * 32];
        float a = xr0[k], b = xr1[k];
        acc0.x += a * w.x; acc0.y += a * w.y; acc0.z += a * w.z; acc0.w += a * w.w;
        acc1.x += b * w.x; acc1.y += b * w.y; acc1.z += b * w.z; acc1.w += b * w.w;
    }
    size_t o0 = (size_t)(n0 + rp * 2) * D1 + c4 * 4;
    *(float4*)(h1 + o0) = acc0;
    *(float4*)(h1 + o0 + D1) = acc1;
}

// ---------------- attention dots layer 1: as1/ad1 [50000,8] ---------------
__global__ __launch_bounds__(256) void k_att1(const float* __restrict__ h1,
                                              const float* __restrict__ asrc,
                                              const float* __restrict__ adst,
                                              float* __restrict__ as1,
                                              float* __restrict__ ad1) {
    int idx = blockIdx.x * 256 + threadIdx.x;     // n*8+h
    if (idx >= N_NODES * H1) return;
    int h = idx & 7;
    const float4* hv = (const float4*)(h1 + (size_t)idx * 16);
    const float4* av = (const float4*)(asrc + h * 16);
    const float4* dv = (const float4*)(adst + h * 16);
    float ss = 0.f, sd = 0.f;
    #pragma unroll
    for (int i = 0; i < 4; ++i) {
        float4 hh = hv[i], aa = av[i], dd = dv[i];
        ss += hh.x*aa.x + hh.y*aa.y + hh.z*aa.z + hh.w*aa.w;
        sd += hh.x*dd.x + hh.y*dd.y + hh.z*dd.z + hh.w*dd.w;
    }
    as1[idx] = ss; ad1[idx] = sd;
}

// ------- aggregation layer 1: wave per node, fused softmax+gather ---------
__global__ __launch_bounds__(256) void k_agg1(const int* __restrict__ basep,
                                              const int* __restrict__ srcs,
                                              const float* __restrict__ h1,
                                              const float* __restrict__ as1,
                                              const float* __restrict__ ad1,
                                              const float* __restrict__ b1,
                                              float* __restrict__ out1) {
    const int w = threadIdx.x >> 6;
    const int l = threadIdx.x & 63;
    const int n = blockIdx.x * 4 + w;          // 12500 blocks exactly
    const int h = l >> 3;                      // head for this lane's channels
    const float adh = ad1[n * 8 + h];
    const int p0 = basep[n], p1 = basep[n + 1];
    float acc0 = 0.f, acc1 = 0.f, se = 0.f;
    for (int p = p0; p < p1; ++p) {
        int s = srcs[p];
        float u = as1[s * 8 + h] + adh;
        u = (u > 0.f) ? u : 0.2f * u;
        float ee = __expf(u);
        se += ee;
        float2 hv = *(const float2*)(h1 + (size_t)s * D1 + l * 2);
        acc0 += ee * hv.x;
        acc1 += ee * hv.y;
    }
    float inv = 1.f / (se + 1e-16f);
    int c = l * 2;
    out1[(size_t)n * D1 + c]     = acc0 * inv + b1[c];
    out1[(size_t)n * D1 + c + 1] = acc1 * inv + b1[c + 1];
}

// ------- GEMM2 (+ReLU on load) + attention dots layer 2 -------------------
__global__ __launch_bounds__(256) void k_gemm2(const float* __restrict__ out1,
                                               const float* __restrict__ W2,
                                               const float* __restrict__ av2,
                                               const float* __restrict__ dv2,
                                               float* __restrict__ h2,
                                               float* __restrict__ as2,
                                               float* __restrict__ ad2) {
    __shared__ float rs[4 * D1];
    const int t = threadIdx.x;
    const int n0 = blockIdx.x * 4;
    #pragma unroll
    for (int i = t; i < 4 * D1; i += 256)
        rs[i] = fmaxf(out1[(size_t)n0 * D1 + i], 0.f);
    __syncthreads();
    const int w = t >> 6;
    const int c = t & 63;
    const int n = n0 + w;
    const float* r = rs + w * D1;
    float acc = 0.f;
    #pragma unroll 8
    for (int k = 0; k < D1; ++k) acc += r[k] * W2[(size_t)k * D2 + c];
    h2[(size_t)n * D2 + c] = acc;
    float ps = acc * av2[c];
    float pd = acc * dv2[c];
    #pragma unroll
    for (int m = 32; m; m >>= 1) { ps += __shfl_xor(ps, m, 64); pd += __shfl_xor(pd, m, 64); }
    if (c == 0) { as2[n] = ps; ad2[n] = pd; }
}

// ------- aggregation layer 2 + bias + log_softmax, wave per node ----------
__global__ __launch_bounds__(256) void k_agg2(const int* __restrict__ basep,
                                              const int* __restrict__ srcs,
                                              const float* __restrict__ h2,
                                              const float* __restrict__ as2,
                                              const float* __restrict__ ad2,
                                              const float* __restrict__ b2,
                                              float* __restrict__ out) {
    const int w = threadIdx.x >> 6;
    const int c = threadIdx.x & 63;
    const int n = blockIdx.x * 4 + w;          // 12500 blocks exactly
    const float ad = ad2[n];
    const int p0 = basep[n], p1 = basep[n + 1];
    float acc = 0.f, se = 0.f;
    for (int p = p0; p < p1; ++p) {
        int s = srcs[p];
        float u = as2[s] + ad;
        u = (u > 0.f) ? u : 0.2f * u;
        float ee = __expf(u);
        se += ee;
        acc += ee * h2[(size_t)s * D2 + c];
    }
    float v = acc / (se + 1e-16f) + b2[c];
    // log_softmax over the wave's 64 channels
    float m = v;
    #pragma unroll
    for (int mask = 32; mask; mask >>= 1) m = fmaxf(m, __shfl_xor(m, mask, 64));
    float ex = __expf(v - m);
    #pragma unroll
    for (int mask = 32; mask; mask >>= 1) ex += __shfl_xor(ex, mask, 64);
    out[(size_t)n * D2 + c] = v - m - __logf(ex);
}

extern "C" void kernel_launch(void* const* d_in, const int* in_sizes, int n_in,
                              void* d_out, int out_size, void* d_ws, size_t ws_size,
                              hipStream_t stream) {
    const float* x     = (const float*)d_in[0];
    const int*   ei    = (const int*)d_in[1];
    const float* W1    = (const float*)d_in[2];
    const float* asrc1 = (const float*)d_in[3];
    const float* adst1 = (const float*)d_in[4];
    const float* b1    = (const float*)d_in[5];
    const float* W2    = (const float*)d_in[6];
    const float* asrc2 = (const float*)d_in[7];
    const float* adst2 = (const float*)d_in[8];
    const float* b2    = (const float*)d_in[9];

    const int E  = in_sizes[1] / 2;   // 800000
    const int ET = E + N_NODES;       // 850000

    // ---- workspace layout ----
    float* fw = (float*)d_ws;
    float* h1   = fw;                                   // N*128
    float* out1 = h1   + (size_t)N_NODES * D1;          // N*128
    float* as1  = out1 + (size_t)N_NODES * D1;          // N*8
    float* ad1  = as1  + (size_t)N_NODES * H1;          // N*8
    float* h2   = ad1  + (size_t)N_NODES * H1;          // N*64
    float* as2  = h2   + (size_t)N_NODES * D2;          // N
    float* ad2  = as2  + N_NODES;                       // N
    int* iw   = (int*)(ad2 + N_NODES);
    int* cnt  = iw;                                     // N
    int* fill = cnt  + N_NODES;                         // N
    int* basep= fill + N_NODES;                         // N+1
    int* aux  = basep + N_NODES + 1;                    // 64
    int* auxs = aux  + 64;                              // 64
    int* srcs = auxs + 64;                              // ET

    const int gE = (ET + 255) / 256;

    k_zero   <<<(N_NODES + 255) / 256, 256, 0, stream>>>(cnt, fill);
    k_hist   <<<gE, 256, 0, stream>>>(ei, E, cnt);
    k_scan1  <<<NSCB, 256, 0, stream>>>(cnt, basep, aux);
    k_scan2  <<<1, 64, 0, stream>>>(aux, auxs);
    k_scan3  <<<(N_NODES + 255) / 256, 256, 0, stream>>>(basep, auxs, ET);
    k_scatter<<<gE, 256, 0, stream>>>(ei, E, basep, fill, srcs);

    k_gemm1  <<<N_NODES / 16, 256, 0, stream>>>(x, W1, h1);
    k_att1   <<<(N_NODES * H1 + 255) / 256, 256, 0, stream>>>(h1, asrc1, adst1, as1, ad1);
    k_agg1   <<<N_NODES / 4, 256, 0, stream>>>(basep, srcs, h1, as1, ad1, b1, out1);
    k_gemm2  <<<N_NODES / 4, 256, 0, stream>>>(out1, W2, asrc2, adst2, h2, as2, ad2);
    k_agg2   <<<N_NODES / 4, 256, 0, stream>>>(basep, srcs, h2, as2, ad2, b2, (float*)d_out);
}

// Round 3
// 361.237 us; speedup vs baseline: 7.8396x; 1.5078x over previous
//
#include <hip/hip_runtime.h>
#include <math.h>

#define N_NODES 50000
#define FIN 512
#define H1 8
#define D1 128   // H1*C1
#define D2 64
#define NSCB ((N_NODES + 1023) >> 10)   // 49 scan blocks

typedef __attribute__((ext_vector_type(4))) float f32x4;
typedef __attribute__((ext_vector_type(8))) __bf16 bf16x8;
typedef __attribute__((ext_vector_type(4))) __bf16 bf16x4;

// ---------------- zero histogram counters --------------------------------
__global__ __launch_bounds__(256) void k_zero(int* __restrict__ cnt, int* __restrict__ fill) {
    int i = blockIdx.x * 256 + threadIdx.x;
    if (i < N_NODES) { cnt[i] = 0; fill[i] = 0; }
}

// ---------------- histogram of dst ---------------------------------------
__global__ __launch_bounds__(256) void k_hist(const int* __restrict__ ei, int E,
                                              int* __restrict__ cnt) {
    int e = blockIdx.x * 256 + threadIdx.x;
    int ET = E + N_NODES;
    if (e >= ET) return;
    int d = (e < E) ? ei[E + e] : (e - E);
    atomicAdd(&cnt[d], 1);
}

// ---------------- scan stage 1: per-block exclusive scan of cnt ----------
__global__ __launch_bounds__(256) void k_scan1(const int* __restrict__ cnt,
                                               int* __restrict__ basep,
                                               int* __restrict__ aux) {
    __shared__ int lds[256];
    int t = threadIdx.x, b = blockIdx.x;
    int g = b * 1024 + t * 4;
    int v0 = (g + 0 < N_NODES) ? cnt[g + 0] : 0;
    int v1 = (g + 1 < N_NODES) ? cnt[g + 1] : 0;
    int v2 = (g + 2 < N_NODES) ? cnt[g + 2] : 0;
    int v3 = (g + 3 < N_NODES) ? cnt[g + 3] : 0;
    int tsum = v0 + v1 + v2 + v3;
    lds[t] = tsum; __syncthreads();
    for (int off = 1; off < 256; off <<= 1) {
        int add = (t >= off) ? lds[t - off] : 0;
        __syncthreads();
        lds[t] += add;
        __syncthreads();
    }
    int excl = lds[t] - tsum;
    if (g + 0 < N_NODES) basep[g + 0] = excl;
    if (g + 1 < N_NODES) basep[g + 1] = excl + v0;
    if (g + 2 < N_NODES) basep[g + 2] = excl + v0 + v1;
    if (g + 3 < N_NODES) basep[g + 3] = excl + v0 + v1 + v2;
    if (t == 255) aux[b] = lds[255];
}

// ---------------- scan stage 2: scan the 49 block sums (one wave) --------
__global__ __launch_bounds__(64) void k_scan2(const int* __restrict__ aux,
                                              int* __restrict__ auxs) {
    int t = threadIdx.x;
    int v = (t < NSCB) ? aux[t] : 0;
    int orig = v;
    for (int off = 1; off < 64; off <<= 1) {
        int x = __shfl_up(v, off, 64);
        if (t >= off) v += x;
    }
    auxs[t] = v - orig;
}

// ---------------- scan stage 3: add block offsets ------------------------
__global__ __launch_bounds__(256) void k_scan3(int* __restrict__ basep,
                                               const int* __restrict__ auxs, int ET) {
    int i = blockIdx.x * 256 + threadIdx.x;
    if (i < N_NODES) basep[i] += auxs[i >> 10];
    if (i == 0) basep[N_NODES] = ET;
}

// ---------------- scatter edges into dst-sorted order --------------------
__global__ __launch_bounds__(256) void k_scatter(const int* __restrict__ ei, int E,
                                                 const int* __restrict__ basep,
                                                 int* __restrict__ fill,
                                                 int* __restrict__ srcs) {
    int e = blockIdx.x * 256 + threadIdx.x;
    int ET = E + N_NODES;
    if (e >= ET) return;
    int s = (e < E) ? ei[e] : (e - E);
    int d = (e < E) ? ei[E + e] : (e - E);
    int pos = basep[d] + atomicAdd(&fill[d], 1);
    srcs[pos] = s;
}

// ---------------- W1 f32 -> bf16, fragment-packed: Wp[k>>3][col][k&7] ----
__global__ __launch_bounds__(256) void k_cvtW(const float* __restrict__ W1,
                                              __bf16* __restrict__ Wp) {
    int idx = blockIdx.x * 256 + threadIdx.x;   // 65536 = 512*128
    int k = idx >> 7, col = idx & 127;
    Wp[(k >> 3) * 1024 + col * 8 + (k & 7)] = (__bf16)W1[idx];
}

// ---------------- GEMM1 (MFMA): h1[50000,128] = x @ W1, bf16 inputs ------
// block tile 64x128, 4 waves in 2x2, KB=64 per step, 8 steps
__global__ __launch_bounds__(256) void k_gemm1(const float* __restrict__ x,
                                               const __bf16* __restrict__ Wp,
                                               float* __restrict__ h1) {
    __shared__ __align__(16) __bf16 As[64 * 64];    // [row][k], XOR-swizzled
    __shared__ __align__(16) __bf16 Bs[64 * 128];   // [kgrp][col][8k], col^kgrp swz
    const int t = threadIdx.x;
    const int l = t & 63;
    const int w = t >> 6;
    const int wr = (w >> 1) * 32, wc = (w & 1) * 64;
    const int n0 = blockIdx.x * 64;

    f32x4 acc[2][4];
    #pragma unroll
    for (int i = 0; i < 2; ++i)
        #pragma unroll
        for (int j = 0; j < 4; ++j) acc[i][j] = (f32x4){0.f, 0.f, 0.f, 0.f};

    const int arow = t >> 4;            // staging row base (0..15)
    const int ak4  = (t & 15) * 4;      // staging k offset (elements)

    for (int s = 0; s < 8; ++s) {
        const int k0 = s * 64;
        // --- stage A: x[n0..n0+64][k0..k0+64] f32 -> bf16, swizzled ---
        #pragma unroll
        for (int i = 0; i < 4; ++i) {
            int row = arow + i * 16;
            int grow = n0 + row;
            float4 f = {0.f, 0.f, 0.f, 0.f};
            if (grow < N_NODES)
                f = *(const float4*)(x + (size_t)grow * FIN + k0 + ak4);
            bf16x4 v = {(__bf16)f.x, (__bf16)f.y, (__bf16)f.z, (__bf16)f.w};
            int eo = (row * 64 + ak4) ^ ((row & 7) << 3);
            *(bf16x4*)(As + eo) = v;
        }
        // --- stage B: linear 16KB copy of packed Wp, col^kgrp swizzle ---
        const uint4* gb = (const uint4*)(Wp + k0 * 128);
        #pragma unroll
        for (int i = 0; i < 4; ++i) {
            int u = t + i * 256;                 // 16B unit: kgrp=u>>7, col=u&127
            uint4 d = gb[u];
            int u2 = u ^ ((u >> 7) & 3);
            *(uint4*)(Bs + u2 * 8) = d;
        }
        __syncthreads();
        // --- MFMA: 2 k-substeps x 2 m-frags x 4 n-frags ---
        #pragma unroll
        for (int ks = 0; ks < 2; ++ks) {
            bf16x8 af[2], bf[4];
            #pragma unroll
            for (int fm = 0; fm < 2; ++fm) {
                int row = wr + fm * 16 + (l & 15);
                int eo = (row * 64 + ks * 32 + (l >> 4) * 8) ^ ((row & 7) << 3);
                af[fm] = *(const bf16x8*)(As + eo);
            }
            #pragma unroll
            for (int fn = 0; fn < 4; ++fn) {
                int col = wc + fn * 16 + (l & 15);
                int kg = ks * 4 + (l >> 4);
                int u = (kg * 128 + col) ^ (kg & 3);
                bf[fn] = *(const bf16x8*)(Bs + u * 8);
            }
            #pragma unroll
            for (int fm = 0; fm < 2; ++fm)
                #pragma unroll
                for (int fn = 0; fn < 4; ++fn)
                    acc[fm][fn] = __builtin_amdgcn_mfma_f32_16x16x32_bf16(
                        af[fm], bf[fn], acc[fm][fn], 0, 0, 0);
        }
        __syncthreads();
    }
    // --- epilogue: C[row][col], row=(l>>4)*4+reg, col=l&15 ---
    #pragma unroll
    for (int fm = 0; fm < 2; ++fm) {
        #pragma unroll
        for (int reg = 0; reg < 4; ++reg) {
            int row = n0 + wr + fm * 16 + (l >> 4) * 4 + reg;
            if (row >= N_NODES) continue;
            #pragma unroll
            for (int fn = 0; fn < 4; ++fn) {
                int col = wc + fn * 16 + (l & 15);
                h1[(size_t)row * D1 + col] = acc[fm][fn][reg];
            }
        }
    }
}

// ---------------- attention dots layer 1: as1/ad1 [50000,8] ---------------
__global__ __launch_bounds__(256) void k_att1(const float* __restrict__ h1,
                                              const float* __restrict__ asrc,
                                              const float* __restrict__ adst,
                                              float* __restrict__ as1,
                                              float* __restrict__ ad1) {
    int idx = blockIdx.x * 256 + threadIdx.x;     // n*8+h
    if (idx >= N_NODES * H1) return;
    int h = idx & 7;
    const float4* hv = (const float4*)(h1 + (size_t)idx * 16);
    const float4* av = (const float4*)(asrc + h * 16);
    const float4* dv = (const float4*)(adst + h * 16);
    float ss = 0.f, sd = 0.f;
    #pragma unroll
    for (int i = 0; i < 4; ++i) {
        float4 hh = hv[i], aa = av[i], dd = dv[i];
        ss += hh.x*aa.x + hh.y*aa.y + hh.z*aa.z + hh.w*aa.w;
        sd += hh.x*dd.x + hh.y*dd.y + hh.z*dd.z + hh.w*dd.w;
    }
    as1[idx] = ss; ad1[idx] = sd;
}

// ------- aggregation layer 1: wave per node, fused softmax+gather ---------
__global__ __launch_bounds__(256) void k_agg1(const int* __restrict__ basep,
                                              const int* __restrict__ srcs,
                                              const float* __restrict__ h1,
                                              const float* __restrict__ as1,
                                              const float* __restrict__ ad1,
                                              const float* __restrict__ b1,
                                              float* __restrict__ out1) {
    const int w = threadIdx.x >> 6;
    const int l = threadIdx.x & 63;
    const int n = blockIdx.x * 4 + w;          // 12500 blocks exactly
    const int h = l >> 3;                      // head for this lane's channels
    const float adh = ad1[n * 8 + h];
    const int p0 = basep[n], p1 = basep[n + 1];
    float acc0 = 0.f, acc1 = 0.f, se = 0.f;
    for (int p = p0; p < p1; ++p) {
        int s = srcs[p];
        float u = as1[s * 8 + h] + adh;
        u = (u > 0.f) ? u : 0.2f * u;
        float ee = __expf(u);
        se += ee;
        float2 hv = *(const float2*)(h1 + (size_t)s * D1 + l * 2);
        acc0 += ee * hv.x;
        acc1 += ee * hv.y;
    }
    float inv = 1.f / (se + 1e-16f);
    int c = l * 2;
    out1[(size_t)n * D1 + c]     = acc0 * inv + b1[c];
    out1[(size_t)n * D1 + c + 1] = acc1 * inv + b1[c + 1];
}

// ------- GEMM2 (+ReLU on load) + attention dots layer 2 -------------------
__global__ __launch_bounds__(256) void k_gemm2(const float* __restrict__ out1,
                                               const float* __restrict__ W2,
                                               const float* __restrict__ av2,
                                               const float* __restrict__ dv2,
                                               float* __restrict__ h2,
                                               float* __restrict__ as2,
                                               float* __restrict__ ad2) {
    __shared__ float rs[4 * D1];
    const int t = threadIdx.x;
    const int n0 = blockIdx.x * 4;
    #pragma unroll
    for (int i = t; i < 4 * D1; i += 256)
        rs[i] = fmaxf(out1[(size_t)n0 * D1 + i], 0.f);
    __syncthreads();
    const int w = t >> 6;
    const int c = t & 63;
    const int n = n0 + w;
    const float* r = rs + w * D1;
    float acc = 0.f;
    #pragma unroll 8
    for (int k = 0; k < D1; ++k) acc += r[k] * W2[(size_t)k * D2 + c];
    h2[(size_t)n * D2 + c] = acc;
    float ps = acc * av2[c];
    float pd = acc * dv2[c];
    #pragma unroll
    for (int m = 32; m; m >>= 1) { ps += __shfl_xor(ps, m, 64); pd += __shfl_xor(pd, m, 64); }
    if (c == 0) { as2[n] = ps; ad2[n] = pd; }
}

// ------- aggregation layer 2 + bias + log_softmax, wave per node ----------
__global__ __launch_bounds__(256) void k_agg2(const int* __restrict__ basep,
                                              const int* __restrict__ srcs,
                                              const float* __restrict__ h2,
                                              const float* __restrict__ as2,
                                              const float* __restrict__ ad2,
                                              const float* __restrict__ b2,
                                              float* __restrict__ out) {
    const int w = threadIdx.x >> 6;
    const int c = threadIdx.x & 63;
    const int n = blockIdx.x * 4 + w;          // 12500 blocks exactly
    const float ad = ad2[n];
    const int p0 = basep[n], p1 = basep[n + 1];
    float acc = 0.f, se = 0.f;
    for (int p = p0; p < p1; ++p) {
        int s = srcs[p];
        float u = as2[s] + ad;
        u = (u > 0.f) ? u : 0.2f * u;
        float ee = __expf(u);
        se += ee;
        acc += ee * h2[(size_t)s * D2 + c];
    }
    float v = acc / (se + 1e-16f) + b2[c];
    // log_softmax over the wave's 64 channels
    float m = v;
    #pragma unroll
    for (int mask = 32; mask; mask >>= 1) m = fmaxf(m, __shfl_xor(m, mask, 64));
    float ex = __expf(v - m);
    #pragma unroll
    for (int mask = 32; mask; mask >>= 1) ex += __shfl_xor(ex, mask, 64);
    out[(size_t)n * D2 + c] = v - m - __logf(ex);
}

extern "C" void kernel_launch(void* const* d_in, const int* in_sizes, int n_in,
                              void* d_out, int out_size, void* d_ws, size_t ws_size,
                              hipStream_t stream) {
    const float* x     = (const float*)d_in[0];
    const int*   ei    = (const int*)d_in[1];
    const float* W1    = (const float*)d_in[2];
    const float* asrc1 = (const float*)d_in[3];
    const float* adst1 = (const float*)d_in[4];
    const float* b1    = (const float*)d_in[5];
    const float* W2    = (const float*)d_in[6];
    const float* asrc2 = (const float*)d_in[7];
    const float* adst2 = (const float*)d_in[8];
    const float* b2    = (const float*)d_in[9];

    const int E  = in_sizes[1] / 2;   // 800000
    const int ET = E + N_NODES;       // 850000

    // ---- workspace layout ----
    float* fw = (float*)d_ws;
    float* h1   = fw;                                   // N*128
    float* out1 = h1   + (size_t)N_NODES * D1;          // N*128
    float* as1  = out1 + (size_t)N_NODES * D1;          // N*8
    float* ad1  = as1  + (size_t)N_NODES * H1;          // N*8
    float* h2   = ad1  + (size_t)N_NODES * H1;          // N*64
    float* as2  = h2   + (size_t)N_NODES * D2;          // N
    float* ad2  = as2  + N_NODES;                       // N
    int* iw   = (int*)(ad2 + N_NODES);
    int* cnt  = iw;                                     // N
    int* fill = cnt  + N_NODES;                         // N
    int* basep= fill + N_NODES;                         // N+1
    int* aux  = basep + N_NODES + 1;                    // 64
    int* auxs = aux  + 64;                              // 64
    int* srcs = auxs + 64;                              // ET
    // bf16 packed W1, 16B-aligned
    uintptr_t wp_addr = ((uintptr_t)(srcs + ET) + 255) & ~(uintptr_t)255;
    __bf16* Wp = (__bf16*)wp_addr;                      // 64K bf16 = 128KB

    const int gE = (ET + 255) / 256;

    k_zero   <<<(N_NODES + 255) / 256, 256, 0, stream>>>(cnt, fill);
    k_hist   <<<gE, 256, 0, stream>>>(ei, E, cnt);
    k_scan1  <<<NSCB, 256, 0, stream>>>(cnt, basep, aux);
    k_scan2  <<<1, 64, 0, stream>>>(aux, auxs);
    k_scan3  <<<(N_NODES + 255) / 256, 256, 0, stream>>>(basep, auxs, ET);
    k_scatter<<<gE, 256, 0, stream>>>(ei, E, basep, fill, srcs);

    k_cvtW   <<<FIN * D1 / 256, 256, 0, stream>>>(W1, Wp);
    k_gemm1  <<<(N_NODES + 63) / 64, 256, 0, stream>>>(x, Wp, h1);
    k_att1   <<<(N_NODES * H1 + 255) / 256, 256, 0, stream>>>(h1, asrc1, adst1, as1, ad1);
    k_agg1   <<<N_NODES / 4, 256, 0, stream>>>(basep, srcs, h1, as1, ad1, b1, out1);
    k_gemm2  <<<N_NODES / 4, 256, 0, stream>>>(out1, W2, asrc2, adst2, h2, as2, ad2);
    k_agg2   <<<N_NODES / 4, 256, 0, stream>>>(basep, srcs, h2, as2, ad2, b2, (float*)d_out);
}

// Round 4
// 290.309 us; speedup vs baseline: 9.7549x; 1.2443x over previous
//
#include <hip/hip_runtime.h>
#include <math.h>

#define N_NODES 50000
#define FIN 512
#define H1 8
#define D1 128   // H1*C1
#define D2 64
#define NSCB ((N_NODES + 1023) >> 10)   // 49 scan blocks

typedef __attribute__((ext_vector_type(4))) float f32x4;
typedef __attribute__((ext_vector_type(8))) __bf16 bf16x8;
typedef __attribute__((ext_vector_type(4))) __bf16 bf16x4;
typedef __attribute__((ext_vector_type(2))) __bf16 bf16x2;

// ---------------- zero histogram counters --------------------------------
__global__ __launch_bounds__(256) void k_zero(int* __restrict__ cnt, int* __restrict__ fill) {
    int i = blockIdx.x * 256 + threadIdx.x;
    if (i < N_NODES) { cnt[i] = 0; fill[i] = 0; }
}

// ---------------- histogram of dst ---------------------------------------
__global__ __launch_bounds__(256) void k_hist(const int* __restrict__ ei, int E,
                                              int* __restrict__ cnt) {
    int e = blockIdx.x * 256 + threadIdx.x;
    int ET = E + N_NODES;
    if (e >= ET) return;
    int d = (e < E) ? ei[E + e] : (e - E);
    atomicAdd(&cnt[d], 1);
}

// ---------------- scan stage 1: per-block exclusive scan of cnt ----------
__global__ __launch_bounds__(256) void k_scan1(const int* __restrict__ cnt,
                                               int* __restrict__ basep,
                                               int* __restrict__ aux) {
    __shared__ int lds[256];
    int t = threadIdx.x, b = blockIdx.x;
    int g = b * 1024 + t * 4;
    int v0 = (g + 0 < N_NODES) ? cnt[g + 0] : 0;
    int v1 = (g + 1 < N_NODES) ? cnt[g + 1] : 0;
    int v2 = (g + 2 < N_NODES) ? cnt[g + 2] : 0;
    int v3 = (g + 3 < N_NODES) ? cnt[g + 3] : 0;
    int tsum = v0 + v1 + v2 + v3;
    lds[t] = tsum; __syncthreads();
    for (int off = 1; off < 256; off <<= 1) {
        int add = (t >= off) ? lds[t - off] : 0;
        __syncthreads();
        lds[t] += add;
        __syncthreads();
    }
    int excl = lds[t] - tsum;
    if (g + 0 < N_NODES) basep[g + 0] = excl;
    if (g + 1 < N_NODES) basep[g + 1] = excl + v0;
    if (g + 2 < N_NODES) basep[g + 2] = excl + v0 + v1;
    if (g + 3 < N_NODES) basep[g + 3] = excl + v0 + v1 + v2;
    if (t == 255) aux[b] = lds[255];
}

// ---------------- scan stage 2: scan the 49 block sums (one wave) --------
__global__ __launch_bounds__(64) void k_scan2(const int* __restrict__ aux,
                                              int* __restrict__ auxs) {
    int t = threadIdx.x;
    int v = (t < NSCB) ? aux[t] : 0;
    int orig = v;
    for (int off = 1; off < 64; off <<= 1) {
        int x = __shfl_up(v, off, 64);
        if (t >= off) v += x;
    }
    auxs[t] = v - orig;
}

// ---------------- scan stage 3: add block offsets ------------------------
__global__ __launch_bounds__(256) void k_scan3(int* __restrict__ basep,
                                               const int* __restrict__ auxs, int ET) {
    int i = blockIdx.x * 256 + threadIdx.x;
    if (i < N_NODES) basep[i] += auxs[i >> 10];
    if (i == 0) basep[N_NODES] = ET;
}

// ---------------- scatter edges into dst-sorted order --------------------
__global__ __launch_bounds__(256) void k_scatter(const int* __restrict__ ei, int E,
                                                 const int* __restrict__ basep,
                                                 int* __restrict__ fill,
                                                 int* __restrict__ srcs) {
    int e = blockIdx.x * 256 + threadIdx.x;
    int ET = E + N_NODES;
    if (e >= ET) return;
    int s = (e < E) ? ei[e] : (e - E);
    int d = (e < E) ? ei[E + e] : (e - E);
    int pos = basep[d] + atomicAdd(&fill[d], 1);
    srcs[pos] = s;
}

// ---------------- W1 f32 -> bf16, fragment-packed: Wp[k>>3][col][k&7] ----
__global__ __launch_bounds__(256) void k_cvtW(const float* __restrict__ W1,
                                              __bf16* __restrict__ Wp) {
    int idx = blockIdx.x * 256 + threadIdx.x;   // 65536 = 512*128
    int k = idx >> 7, col = idx & 127;
    Wp[(k >> 3) * 1024 + col * 8 + (k & 7)] = (__bf16)W1[idx];
}

// ---------------- GEMM1 (MFMA): h1b[50000,128] bf16 = x @ W1 -------------
// block tile 64x128, 4 waves in 2x2, KB=64 per step, 8 steps
__global__ __launch_bounds__(256) void k_gemm1(const float* __restrict__ x,
                                               const __bf16* __restrict__ Wp,
                                               __bf16* __restrict__ h1b) {
    __shared__ __align__(16) __bf16 As[64 * 64];    // [row][k], XOR-swizzled
    __shared__ __align__(16) __bf16 Bs[64 * 128];   // [kgrp][col][8k], col^kgrp swz
    const int t = threadIdx.x;
    const int l = t & 63;
    const int w = t >> 6;
    const int wr = (w >> 1) * 32, wc = (w & 1) * 64;
    const int n0 = blockIdx.x * 64;

    f32x4 acc[2][4];
    #pragma unroll
    for (int i = 0; i < 2; ++i)
        #pragma unroll
        for (int j = 0; j < 4; ++j) acc[i][j] = (f32x4){0.f, 0.f, 0.f, 0.f};

    const int arow = t >> 4;            // staging row base (0..15)
    const int ak4  = (t & 15) * 4;      // staging k offset (elements)

    for (int s = 0; s < 8; ++s) {
        const int k0 = s * 64;
        // --- stage A: x[n0..n0+64][k0..k0+64] f32 -> bf16, swizzled ---
        #pragma unroll
        for (int i = 0; i < 4; ++i) {
            int row = arow + i * 16;
            int grow = n0 + row;
            float4 f = {0.f, 0.f, 0.f, 0.f};
            if (grow < N_NODES)
                f = *(const float4*)(x + (size_t)grow * FIN + k0 + ak4);
            bf16x4 v = {(__bf16)f.x, (__bf16)f.y, (__bf16)f.z, (__bf16)f.w};
            int eo = (row * 64 + ak4) ^ ((row & 7) << 3);
            *(bf16x4*)(As + eo) = v;
        }
        // --- stage B: linear 16KB copy of packed Wp, col^kgrp swizzle ---
        const uint4* gb = (const uint4*)(Wp + k0 * 128);
        #pragma unroll
        for (int i = 0; i < 4; ++i) {
            int u = t + i * 256;                 // 16B unit: kgrp=u>>7, col=u&127
            uint4 d = gb[u];
            int u2 = u ^ ((u >> 7) & 3);
            *(uint4*)(Bs + u2 * 8) = d;
        }
        __syncthreads();
        // --- MFMA: 2 k-substeps x 2 m-frags x 4 n-frags ---
        #pragma unroll
        for (int ks = 0; ks < 2; ++ks) {
            bf16x8 af[2], bf[4];
            #pragma unroll
            for (int fm = 0; fm < 2; ++fm) {
                int row = wr + fm * 16 + (l & 15);
                int eo = (row * 64 + ks * 32 + (l >> 4) * 8) ^ ((row & 7) << 3);
                af[fm] = *(const bf16x8*)(As + eo);
            }
            #pragma unroll
            for (int fn = 0; fn < 4; ++fn) {
                int col = wc + fn * 16 + (l & 15);
                int kg = ks * 4 + (l >> 4);
                int u = (kg * 128 + col) ^ (kg & 3);
                bf[fn] = *(const bf16x8*)(Bs + u * 8);
            }
            #pragma unroll
            for (int fm = 0; fm < 2; ++fm)
                #pragma unroll
                for (int fn = 0; fn < 4; ++fn)
                    acc[fm][fn] = __builtin_amdgcn_mfma_f32_16x16x32_bf16(
                        af[fm], bf[fn], acc[fm][fn], 0, 0, 0);
        }
        __syncthreads();
    }
    // --- epilogue: C[row][col] -> bf16, row=(l>>4)*4+reg, col=l&15 ---
    #pragma unroll
    for (int fm = 0; fm < 2; ++fm) {
        #pragma unroll
        for (int reg = 0; reg < 4; ++reg) {
            int row = n0 + wr + fm * 16 + (l >> 4) * 4 + reg;
            if (row >= N_NODES) continue;
            #pragma unroll
            for (int fn = 0; fn < 4; ++fn) {
                int col = wc + fn * 16 + (l & 15);
                h1b[(size_t)row * D1 + col] = (__bf16)acc[fm][fn][reg];
            }
        }
    }
}

// ---------------- attention dots layer 1 (bf16 h1) ------------------------
__global__ __launch_bounds__(256) void k_att1(const __bf16* __restrict__ h1b,
                                              const float* __restrict__ asrc,
                                              const float* __restrict__ adst,
                                              float* __restrict__ as1,
                                              float* __restrict__ ad1) {
    int idx = blockIdx.x * 256 + threadIdx.x;     // n*8+h
    if (idx >= N_NODES * H1) return;
    int h = idx & 7;
    const bf16x8* hv = (const bf16x8*)(h1b + (size_t)idx * 16);
    bf16x8 ha = hv[0], hb = hv[1];
    float hs[16];
    #pragma unroll
    for (int i = 0; i < 8; ++i) { hs[i] = (float)ha[i]; hs[8 + i] = (float)hb[i]; }
    const float* av = asrc + h * 16;
    const float* dv = adst + h * 16;
    float ss = 0.f, sd = 0.f;
    #pragma unroll
    for (int i = 0; i < 16; ++i) { ss += hs[i] * av[i]; sd += hs[i] * dv[i]; }
    as1[idx] = ss; ad1[idx] = sd;
}

// ------- aggregation layer 1: wave/node, chunked index broadcast ----------
__global__ __launch_bounds__(256) void k_agg1(const int* __restrict__ basep,
                                              const int* __restrict__ srcs,
                                              const __bf16* __restrict__ h1b,
                                              const float* __restrict__ as1,
                                              const float* __restrict__ ad1,
                                              const float* __restrict__ b1,
                                              float* __restrict__ out1) {
    const int w = threadIdx.x >> 6;
    const int l = threadIdx.x & 63;
    const int n = blockIdx.x * 4 + w;          // 12500 blocks exactly
    const int h = l >> 3;                      // head for this lane's channels
    const float adh = ad1[n * 8 + h];
    const int p0 = basep[n], p1 = basep[n + 1];
    float acc0 = 0.f, acc1 = 0.f, se = 0.f;
    for (int base = p0; base < p1; base += 64) {
        int my = (base + l < p1) ? srcs[base + l] : 0;
        int m = min(64, p1 - base);
        #pragma unroll 4
        for (int j = 0; j < m; ++j) {
            int s = __shfl(my, j, 64);
            float u = as1[s * 8 + h] + adh;
            u = (u > 0.f) ? u : 0.2f * u;
            float ee = __expf(u);
            se += ee;
            bf16x2 hv = *(const bf16x2*)(h1b + (size_t)s * D1 + l * 2);
            acc0 += ee * (float)hv.x;
            acc1 += ee * (float)hv.y;
        }
    }
    float inv = 1.f / (se + 1e-16f);
    int c = l * 2;
    out1[(size_t)n * D1 + c]     = acc0 * inv + b1[c];
    out1[(size_t)n * D1 + c + 1] = acc1 * inv + b1[c + 1];
}

// ------- GEMM2 (+ReLU on load) + attention dots layer 2, bf16 h2 out ------
__global__ __launch_bounds__(256) void k_gemm2(const float* __restrict__ out1,
                                               const float* __restrict__ W2,
                                               const float* __restrict__ av2,
                                               const float* __restrict__ dv2,
                                               __bf16* __restrict__ h2b,
                                               float* __restrict__ as2,
                                               float* __restrict__ ad2) {
    __shared__ float rs[4 * D1];
    const int t = threadIdx.x;
    const int n0 = blockIdx.x * 4;
    #pragma unroll
    for (int i = t; i < 4 * D1; i += 256)
        rs[i] = fmaxf(out1[(size_t)n0 * D1 + i], 0.f);
    __syncthreads();
    const int w = t >> 6;
    const int c = t & 63;
    const int n = n0 + w;
    const float* r = rs + w * D1;
    float acc = 0.f;
    #pragma unroll 8
    for (int k = 0; k < D1; ++k) acc += r[k] * W2[(size_t)k * D2 + c];
    h2b[(size_t)n * D2 + c] = (__bf16)acc;
    float ps = acc * av2[c];
    float pd = acc * dv2[c];
    #pragma unroll
    for (int m = 32; m; m >>= 1) { ps += __shfl_xor(ps, m, 64); pd += __shfl_xor(pd, m, 64); }
    if (c == 0) { as2[n] = ps; ad2[n] = pd; }
}

// ------- aggregation layer 2 + bias + log_softmax -------------------------
// wave per node; 2 edges/iter: lanes 0-31 even edge, 32-63 odd edge,
// each lane handles a channel PAIR (bf16x2 = 4B gather).
__global__ __launch_bounds__(256) void k_agg2(const int* __restrict__ basep,
                                              const int* __restrict__ srcs,
                                              const __bf16* __restrict__ h2b,
                                              const float* __restrict__ as2,
                                              const float* __restrict__ ad2,
                                              const float* __restrict__ b2,
                                              float* __restrict__ out) {
    const int w = threadIdx.x >> 6;
    const int l = threadIdx.x & 63;
    const int half = l >> 5;                   // 0: even edges, 1: odd edges
    const int c2 = l & 31;                     // channel pair index
    const int n = blockIdx.x * 4 + w;          // 12500 blocks exactly
    const float ad = ad2[n];
    const int p0 = basep[n], p1 = basep[n + 1];
    float acc0 = 0.f, acc1 = 0.f, se = 0.f;
    for (int base = p0; base < p1; base += 64) {
        int my = (base + l < p1) ? srcs[base + l] : 0;
        int m = min(64, p1 - base);
        #pragma unroll 2
        for (int j2 = 0; j2 < m; j2 += 2) {
            int j = j2 + half;
            bool ok = j < m;
            int s = __shfl(my, ok ? j : 0, 64);
            if (ok) {
                float u = as2[s] + ad;
                u = (u > 0.f) ? u : 0.2f * u;
                float ee = __expf(u);
                se += ee;
                bf16x2 hv = *(const bf16x2*)(h2b + (size_t)s * D2 + c2 * 2);
                acc0 += ee * (float)hv.x;
                acc1 += ee * (float)hv.y;
            }
        }
    }
    // combine the two edge-halves (lanes i and i+32 hold same channel pair)
    acc0 += __shfl_xor(acc0, 32, 64);
    acc1 += __shfl_xor(acc1, 32, 64);
    se   += __shfl_xor(se, 32, 64);
    float inv = 1.f / (se + 1e-16f);
    float v0 = acc0 * inv + b2[c2 * 2];
    float v1 = acc1 * inv + b2[c2 * 2 + 1];
    // log_softmax over 64 channels (2 per lane, duplicated across halves)
    float mx = fmaxf(v0, v1);
    #pragma unroll
    for (int mask = 16; mask; mask >>= 1) mx = fmaxf(mx, __shfl_xor(mx, mask, 64));
    float ex = __expf(v0 - mx) + __expf(v1 - mx);
    #pragma unroll
    for (int mask = 16; mask; mask >>= 1) ex += __shfl_xor(ex, mask, 64);
    float lse = mx + __logf(ex);
    if (half == 0) {
        float2 r = {v0 - lse, v1 - lse};
        *(float2*)(out + (size_t)n * D2 + c2 * 2) = r;
    }
}

extern "C" void kernel_launch(void* const* d_in, const int* in_sizes, int n_in,
                              void* d_out, int out_size, void* d_ws, size_t ws_size,
                              hipStream_t stream) {
    const float* x     = (const float*)d_in[0];
    const int*   ei    = (const int*)d_in[1];
    const float* W1    = (const float*)d_in[2];
    const float* asrc1 = (const float*)d_in[3];
    const float* adst1 = (const float*)d_in[4];
    const float* b1    = (const float*)d_in[5];
    const float* W2    = (const float*)d_in[6];
    const float* asrc2 = (const float*)d_in[7];
    const float* adst2 = (const float*)d_in[8];
    const float* b2    = (const float*)d_in[9];

    const int E  = in_sizes[1] / 2;   // 800000
    const int ET = E + N_NODES;       // 850000

    // ---- workspace layout ----
    float* fw = (float*)d_ws;
    float* out1 = fw;                                   // N*128
    float* as1  = out1 + (size_t)N_NODES * D1;          // N*8
    float* ad1  = as1  + (size_t)N_NODES * H1;          // N*8
    float* as2  = ad1  + (size_t)N_NODES * H1;          // N
    float* ad2  = as2  + N_NODES;                       // N
    int* iw   = (int*)(ad2 + N_NODES);
    int* cnt  = iw;                                     // N
    int* fill = cnt  + N_NODES;                         // N
    int* basep= fill + N_NODES;                         // N+1
    int* aux  = basep + N_NODES + 1;                    // 64
    int* auxs = aux  + 64;                              // 64
    int* srcs = auxs + 64;                              // ET
    uintptr_t pa = ((uintptr_t)(srcs + ET) + 255) & ~(uintptr_t)255;
    __bf16* Wp  = (__bf16*)pa;                          // 64K bf16 = 128KB
    __bf16* h1b = Wp + (size_t)FIN * D1;                // N*128 bf16 (256B-aligned)
    __bf16* h2b = h1b + (size_t)N_NODES * D1;           // N*64 bf16

    const int gE = (ET + 255) / 256;

    k_zero   <<<(N_NODES + 255) / 256, 256, 0, stream>>>(cnt, fill);
    k_hist   <<<gE, 256, 0, stream>>>(ei, E, cnt);
    k_scan1  <<<NSCB, 256, 0, stream>>>(cnt, basep, aux);
    k_scan2  <<<1, 64, 0, stream>>>(aux, auxs);
    k_scan3  <<<(N_NODES + 255) / 256, 256, 0, stream>>>(basep, auxs, ET);
    k_scatter<<<gE, 256, 0, stream>>>(ei, E, basep, fill, srcs);

    k_cvtW   <<<FIN * D1 / 256, 256, 0, stream>>>(W1, Wp);
    k_gemm1  <<<(N_NODES + 63) / 64, 256, 0, stream>>>(x, Wp, h1b);
    k_att1   <<<(N_NODES * H1 + 255) / 256, 256, 0, stream>>>(h1b, asrc1, adst1, as1, ad1);
    k_agg1   <<<N_NODES / 4, 256, 0, stream>>>(basep, srcs, h1b, as1, ad1, b1, out1);
    k_gemm2  <<<N_NODES / 4, 256, 0, stream>>>(out1, W2, asrc2, adst2, h2b, as2, ad2);
    k_agg2   <<<N_NODES / 4, 256, 0, stream>>>(basep, srcs, h2b, as2, ad2, b2, (float*)d_out);
}

// Round 5
// 264.623 us; speedup vs baseline: 10.7018x; 1.0971x over previous
//
#include <hip/hip_runtime.h>
#include <math.h>

#define N_NODES 50000
#define FIN 512
#define H1 8
#define D1 128   // H1*C1
#define D2 64
#define NSCB ((N_NODES + 1023) >> 10)   // 49 scan blocks

typedef __attribute__((ext_vector_type(4))) float f32x4;
typedef __attribute__((ext_vector_type(8))) __bf16 bf16x8;
typedef __attribute__((ext_vector_type(4))) __bf16 bf16x4;
typedef __attribute__((ext_vector_type(2))) __bf16 bf16x2;

// ---------------- zero histogram counters --------------------------------
__global__ __launch_bounds__(256) void k_zero(int* __restrict__ cnt, int* __restrict__ fill) {
    int i = blockIdx.x * 256 + threadIdx.x;
    if (i < N_NODES) { cnt[i] = 0; fill[i] = 0; }
}

// ---------------- histogram of dst ---------------------------------------
__global__ __launch_bounds__(256) void k_hist(const int* __restrict__ ei, int E,
                                              int* __restrict__ cnt) {
    int e = blockIdx.x * 256 + threadIdx.x;
    int ET = E + N_NODES;
    if (e >= ET) return;
    int d = (e < E) ? ei[E + e] : (e - E);
    atomicAdd(&cnt[d], 1);
}

// ---------------- scan stage 1: per-block exclusive scan of cnt ----------
__global__ __launch_bounds__(256) void k_scan1(const int* __restrict__ cnt,
                                               int* __restrict__ basep,
                                               int* __restrict__ aux) {
    __shared__ int lds[256];
    int t = threadIdx.x, b = blockIdx.x;
    int g = b * 1024 + t * 4;
    int v0 = (g + 0 < N_NODES) ? cnt[g + 0] : 0;
    int v1 = (g + 1 < N_NODES) ? cnt[g + 1] : 0;
    int v2 = (g + 2 < N_NODES) ? cnt[g + 2] : 0;
    int v3 = (g + 3 < N_NODES) ? cnt[g + 3] : 0;
    int tsum = v0 + v1 + v2 + v3;
    lds[t] = tsum; __syncthreads();
    for (int off = 1; off < 256; off <<= 1) {
        int add = (t >= off) ? lds[t - off] : 0;
        __syncthreads();
        lds[t] += add;
        __syncthreads();
    }
    int excl = lds[t] - tsum;
    if (g + 0 < N_NODES) basep[g + 0] = excl;
    if (g + 1 < N_NODES) basep[g + 1] = excl + v0;
    if (g + 2 < N_NODES) basep[g + 2] = excl + v0 + v1;
    if (g + 3 < N_NODES) basep[g + 3] = excl + v0 + v1 + v2;
    if (t == 255) aux[b] = lds[255];
}

// ---------------- scan stage 2: scan the 49 block sums (one wave) --------
__global__ __launch_bounds__(64) void k_scan2(const int* __restrict__ aux,
                                              int* __restrict__ auxs) {
    int t = threadIdx.x;
    int v = (t < NSCB) ? aux[t] : 0;
    int orig = v;
    for (int off = 1; off < 64; off <<= 1) {
        int x = __shfl_up(v, off, 64);
        if (t >= off) v += x;
    }
    auxs[t] = v - orig;
}

// ---------------- scan stage 3: add block offsets ------------------------
__global__ __launch_bounds__(256) void k_scan3(int* __restrict__ basep,
                                               const int* __restrict__ auxs, int ET) {
    int i = blockIdx.x * 256 + threadIdx.x;
    if (i < N_NODES) basep[i] += auxs[i >> 10];
    if (i == 0) basep[N_NODES] = ET;
}

// ---------------- scatter edges into dst-sorted order --------------------
__global__ __launch_bounds__(256) void k_scatter(const int* __restrict__ ei, int E,
                                                 const int* __restrict__ basep,
                                                 int* __restrict__ fill,
                                                 int* __restrict__ srcs,
                                                 int* __restrict__ dsts) {
    int e = blockIdx.x * 256 + threadIdx.x;
    int ET = E + N_NODES;
    if (e >= ET) return;
    int s = (e < E) ? ei[e] : (e - E);
    int d = (e < E) ? ei[E + e] : (e - E);
    int pos = basep[d] + atomicAdd(&fill[d], 1);
    srcs[pos] = s;
    dsts[pos] = d;
}

// ---------------- W1 f32 -> bf16, fragment-packed: Wp[k>>3][col][k&7] ----
__global__ __launch_bounds__(256) void k_cvtW(const float* __restrict__ W1,
                                              __bf16* __restrict__ Wp) {
    int idx = blockIdx.x * 256 + threadIdx.x;   // 65536 = 512*128
    int k = idx >> 7, col = idx & 127;
    Wp[(k >> 3) * 1024 + col * 8 + (k & 7)] = (__bf16)W1[idx];
}

// ---------------- GEMM1 (MFMA): h1b[50000,128] bf16 = x @ W1 -------------
// block tile 64x128, 4 waves in 2x2, KB=64 per step, 8 steps
__global__ __launch_bounds__(256) void k_gemm1(const float* __restrict__ x,
                                               const __bf16* __restrict__ Wp,
                                               __bf16* __restrict__ h1b) {
    __shared__ __align__(16) __bf16 As[64 * 64];    // [row][k], XOR-swizzled
    __shared__ __align__(16) __bf16 Bs[64 * 128];   // [kgrp][col][8k], col^kgrp swz
    const int t = threadIdx.x;
    const int l = t & 63;
    const int w = t >> 6;
    const int wr = (w >> 1) * 32, wc = (w & 1) * 64;
    const int n0 = blockIdx.x * 64;

    f32x4 acc[2][4];
    #pragma unroll
    for (int i = 0; i < 2; ++i)
        #pragma unroll
        for (int j = 0; j < 4; ++j) acc[i][j] = (f32x4){0.f, 0.f, 0.f, 0.f};

    const int arow = t >> 4;            // staging row base (0..15)
    const int ak4  = (t & 15) * 4;      // staging k offset (elements)

    for (int s = 0; s < 8; ++s) {
        const int k0 = s * 64;
        // --- stage A: x[n0..n0+64][k0..k0+64] f32 -> bf16, swizzled ---
        #pragma unroll
        for (int i = 0; i < 4; ++i) {
            int row = arow + i * 16;
            int grow = n0 + row;
            float4 f = {0.f, 0.f, 0.f, 0.f};
            if (grow < N_NODES)
                f = *(const float4*)(x + (size_t)grow * FIN + k0 + ak4);
            bf16x4 v = {(__bf16)f.x, (__bf16)f.y, (__bf16)f.z, (__bf16)f.w};
            int eo = (row * 64 + ak4) ^ ((row & 7) << 3);
            *(bf16x4*)(As + eo) = v;
        }
        // --- stage B: linear 16KB copy of packed Wp, col^kgrp swizzle ---
        const uint4* gb = (const uint4*)(Wp + k0 * 128);
        #pragma unroll
        for (int i = 0; i < 4; ++i) {
            int u = t + i * 256;                 // 16B unit: kgrp=u>>7, col=u&127
            uint4 d = gb[u];
            int u2 = u ^ ((u >> 7) & 3);
            *(uint4*)(Bs + u2 * 8) = d;
        }
        __syncthreads();
        // --- MFMA: 2 k-substeps x 2 m-frags x 4 n-frags ---
        #pragma unroll
        for (int ks = 0; ks < 2; ++ks) {
            bf16x8 af[2], bf[4];
            #pragma unroll
            for (int fm = 0; fm < 2; ++fm) {
                int row = wr + fm * 16 + (l & 15);
                int eo = (row * 64 + ks * 32 + (l >> 4) * 8) ^ ((row & 7) << 3);
                af[fm] = *(const bf16x8*)(As + eo);
            }
            #pragma unroll
            for (int fn = 0; fn < 4; ++fn) {
                int col = wc + fn * 16 + (l & 15);
                int kg = ks * 4 + (l >> 4);
                int u = (kg * 128 + col) ^ (kg & 3);
                bf[fn] = *(const bf16x8*)(Bs + u * 8);
            }
            #pragma unroll
            for (int fm = 0; fm < 2; ++fm)
                #pragma unroll
                for (int fn = 0; fn < 4; ++fn)
                    acc[fm][fn] = __builtin_amdgcn_mfma_f32_16x16x32_bf16(
                        af[fm], bf[fn], acc[fm][fn], 0, 0, 0);
        }
        __syncthreads();
    }
    // --- epilogue: C[row][col] -> bf16, row=(l>>4)*4+reg, col=l&15 ---
    #pragma unroll
    for (int fm = 0; fm < 2; ++fm) {
        #pragma unroll
        for (int reg = 0; reg < 4; ++reg) {
            int row = n0 + wr + fm * 16 + (l >> 4) * 4 + reg;
            if (row >= N_NODES) continue;
            #pragma unroll
            for (int fn = 0; fn < 4; ++fn) {
                int col = wc + fn * 16 + (l & 15);
                h1b[(size_t)row * D1 + col] = (__bf16)acc[fm][fn][reg];
            }
        }
    }
}

// ---------------- attention dots layer 1 (bf16 h1) ------------------------
__global__ __launch_bounds__(256) void k_att1(const __bf16* __restrict__ h1b,
                                              const float* __restrict__ asrc,
                                              const float* __restrict__ adst,
                                              float* __restrict__ as1,
                                              float* __restrict__ ad1) {
    int idx = blockIdx.x * 256 + threadIdx.x;     // n*8+h
    if (idx >= N_NODES * H1) return;
    int h = idx & 7;
    const bf16x8* hv = (const bf16x8*)(h1b + (size_t)idx * 16);
    bf16x8 ha = hv[0], hb = hv[1];
    float hs[16];
    #pragma unroll
    for (int i = 0; i < 8; ++i) { hs[i] = (float)ha[i]; hs[8 + i] = (float)hb[i]; }
    const float* av = asrc + h * 16;
    const float* dv = adst + h * 16;
    float ss = 0.f, sd = 0.f;
    #pragma unroll
    for (int i = 0; i < 16; ++i) { ss += hs[i] * av[i]; sd += hs[i] * dv[i]; }
    as1[idx] = ss; ad1[idx] = sd;
}

// ------- edge pass 1: lane per edge, ee1[p][8] = exp(leaky(as+ad)) --------
__global__ __launch_bounds__(256) void k_edge1(const int* __restrict__ srcs,
                                               const int* __restrict__ dsts,
                                               const float* __restrict__ as1,
                                               const float* __restrict__ ad1,
                                               float* __restrict__ ee1, int ET) {
    int p = blockIdx.x * 256 + threadIdx.x;
    if (p >= ET) return;
    int s = srcs[p], d = dsts[p];
    const float4* av = (const float4*)(as1 + (size_t)s * 8);
    const float4* dv = (const float4*)(ad1 + (size_t)d * 8);
    float4 a0 = av[0], a1 = av[1], b0 = dv[0], b1 = dv[1];
    float u[8] = {a0.x + b0.x, a0.y + b0.y, a0.z + b0.z, a0.w + b0.w,
                  a1.x + b1.x, a1.y + b1.y, a1.z + b1.z, a1.w + b1.w};
    float ee[8];
    #pragma unroll
    for (int h = 0; h < 8; ++h) {
        float v = u[h];
        v = (v > 0.f) ? v : 0.2f * v;
        ee[h] = __expf(v);
    }
    float4* eo = (float4*)(ee1 + (size_t)p * 8);
    eo[0] = make_float4(ee[0], ee[1], ee[2], ee[3]);
    eo[1] = make_float4(ee[4], ee[5], ee[6], ee[7]);
}

// ------- aggregation layer 1: wave/node, 2 edges/iter, 4ch/lane -----------
__global__ __launch_bounds__(256) void k_agg1(const int* __restrict__ basep,
                                              const int* __restrict__ srcs,
                                              const float* __restrict__ ee1,
                                              const __bf16* __restrict__ h1b,
                                              const float* __restrict__ b1,
                                              float* __restrict__ out1) {
    const int w = threadIdx.x >> 6;
    const int l = threadIdx.x & 63;
    const int half = l >> 5;                   // which edge of the pair
    const int c4 = (l & 31) * 4;               // 4 channels per lane
    const int h = c4 >> 4;                     // head of this channel group
    const int n = blockIdx.x * 4 + w;          // 12500 blocks exactly
    const int p0 = basep[n], p1 = basep[n + 1];
    float a0 = 0.f, a1 = 0.f, a2 = 0.f, a3 = 0.f, se = 0.f;
    const int m = p1 - p0;
    #pragma unroll 2
    for (int j2 = 0; j2 < m; j2 += 2) {
        int j = j2 + half;
        bool ok = j < m;
        int p = p0 + (ok ? j : 0);
        int s = srcs[p];
        float ee = ee1[(size_t)p * 8 + h];
        if (!ok) ee = 0.f;
        se += ee;
        bf16x4 hv = *(const bf16x4*)(h1b + (size_t)s * D1 + c4);
        a0 += ee * (float)hv.x;
        a1 += ee * (float)hv.y;
        a2 += ee * (float)hv.z;
        a3 += ee * (float)hv.w;
    }
    a0 += __shfl_xor(a0, 32, 64);
    a1 += __shfl_xor(a1, 32, 64);
    a2 += __shfl_xor(a2, 32, 64);
    a3 += __shfl_xor(a3, 32, 64);
    se += __shfl_xor(se, 32, 64);
    if (half == 0) {
        float inv = 1.f / (se + 1e-16f);
        float4 r = {a0 * inv + b1[c4], a1 * inv + b1[c4 + 1],
                    a2 * inv + b1[c4 + 2], a3 * inv + b1[c4 + 3]};
        *(float4*)(out1 + (size_t)n * D1 + c4) = r;
    }
}

// ------- GEMM2 (+ReLU on load) + attention dots layer 2, bf16 h2 out ------
__global__ __launch_bounds__(256) void k_gemm2(const float* __restrict__ out1,
                                               const float* __restrict__ W2,
                                               const float* __restrict__ av2,
                                               const float* __restrict__ dv2,
                                               __bf16* __restrict__ h2b,
                                               float* __restrict__ as2,
                                               float* __restrict__ ad2) {
    __shared__ float rs[4 * D1];
    const int t = threadIdx.x;
    const int n0 = blockIdx.x * 4;
    #pragma unroll
    for (int i = t; i < 4 * D1; i += 256)
        rs[i] = fmaxf(out1[(size_t)n0 * D1 + i], 0.f);
    __syncthreads();
    const int w = t >> 6;
    const int c = t & 63;
    const int n = n0 + w;
    const float* r = rs + w * D1;
    float acc = 0.f;
    #pragma unroll 8
    for (int k = 0; k < D1; ++k) acc += r[k] * W2[(size_t)k * D2 + c];
    h2b[(size_t)n * D2 + c] = (__bf16)acc;
    float ps = acc * av2[c];
    float pd = acc * dv2[c];
    #pragma unroll
    for (int m = 32; m; m >>= 1) { ps += __shfl_xor(ps, m, 64); pd += __shfl_xor(pd, m, 64); }
    if (c == 0) { as2[n] = ps; ad2[n] = pd; }
}

// ------- edge pass 2: lane per edge, ee2[p] -------------------------------
__global__ __launch_bounds__(256) void k_edge2(const int* __restrict__ srcs,
                                               const int* __restrict__ dsts,
                                               const float* __restrict__ as2,
                                               const float* __restrict__ ad2,
                                               float* __restrict__ ee2, int ET) {
    int p = blockIdx.x * 256 + threadIdx.x;
    if (p >= ET) return;
    float u = as2[srcs[p]] + ad2[dsts[p]];
    u = (u > 0.f) ? u : 0.2f * u;
    ee2[p] = __expf(u);
}

// ------- aggregation layer 2 + bias + log_softmax, 4 edges/iter -----------
__global__ __launch_bounds__(256) void k_agg2(const int* __restrict__ basep,
                                              const int* __restrict__ srcs,
                                              const float* __restrict__ ee2,
                                              const __bf16* __restrict__ h2b,
                                              const float* __restrict__ b2,
                                              float* __restrict__ out) {
    const int w = threadIdx.x >> 6;
    const int l = threadIdx.x & 63;
    const int q = l >> 4;                      // edge slot within quad
    const int c4 = (l & 15) * 4;               // 4 channels per lane
    const int n = blockIdx.x * 4 + w;          // 12500 blocks exactly
    const int p0 = basep[n], p1 = basep[n + 1];
    float a0 = 0.f, a1 = 0.f, a2 = 0.f, a3 = 0.f, se = 0.f;
    const int m = p1 - p0;
    #pragma unroll 2
    for (int j4 = 0; j4 < m; j4 += 4) {
        int j = j4 + q;
        bool ok = j < m;
        int p = p0 + (ok ? j : 0);
        int s = srcs[p];
        float ee = ee2[p];
        if (!ok) ee = 0.f;
        se += ee;
        bf16x4 hv = *(const bf16x4*)(h2b + (size_t)s * D2 + c4);
        a0 += ee * (float)hv.x;
        a1 += ee * (float)hv.y;
        a2 += ee * (float)hv.z;
        a3 += ee * (float)hv.w;
    }
    #pragma unroll
    for (int mk = 16; mk <= 32; mk <<= 1) {
        a0 += __shfl_xor(a0, mk, 64);
        a1 += __shfl_xor(a1, mk, 64);
        a2 += __shfl_xor(a2, mk, 64);
        a3 += __shfl_xor(a3, mk, 64);
        se += __shfl_xor(se, mk, 64);
    }
    float inv = 1.f / (se + 1e-16f);
    float v0 = a0 * inv + b2[c4];
    float v1 = a1 * inv + b2[c4 + 1];
    float v2 = a2 * inv + b2[c4 + 2];
    float v3 = a3 * inv + b2[c4 + 3];
    // log_softmax over 64 channels (held by 16 lanes, duplicated in quads)
    float mx = fmaxf(fmaxf(v0, v1), fmaxf(v2, v3));
    #pragma unroll
    for (int mk = 1; mk <= 8; mk <<= 1) mx = fmaxf(mx, __shfl_xor(mx, mk, 64));
    float ex = __expf(v0 - mx) + __expf(v1 - mx) + __expf(v2 - mx) + __expf(v3 - mx);
    #pragma unroll
    for (int mk = 1; mk <= 8; mk <<= 1) ex += __shfl_xor(ex, mk, 64);
    float lse = mx + __logf(ex);
    if (q == 0) {
        float4 r = {v0 - lse, v1 - lse, v2 - lse, v3 - lse};
        *(float4*)(out + (size_t)n * D2 + c4) = r;
    }
}

extern "C" void kernel_launch(void* const* d_in, const int* in_sizes, int n_in,
                              void* d_out, int out_size, void* d_ws, size_t ws_size,
                              hipStream_t stream) {
    const float* x     = (const float*)d_in[0];
    const int*   ei    = (const int*)d_in[1];
    const float* W1    = (const float*)d_in[2];
    const float* asrc1 = (const float*)d_in[3];
    const float* adst1 = (const float*)d_in[4];
    const float* b1    = (const float*)d_in[5];
    const float* W2    = (const float*)d_in[6];
    const float* asrc2 = (const float*)d_in[7];
    const float* adst2 = (const float*)d_in[8];
    const float* b2    = (const float*)d_in[9];

    const int E  = in_sizes[1] / 2;   // 800000
    const int ET = E + N_NODES;       // 850000

    // ---- workspace layout ----
    float* fw = (float*)d_ws;
    float* out1 = fw;                                   // N*128
    float* as1  = out1 + (size_t)N_NODES * D1;          // N*8
    float* ad1  = as1  + (size_t)N_NODES * H1;          // N*8
    float* as2  = ad1  + (size_t)N_NODES * H1;          // N
    float* ad2  = as2  + N_NODES;                       // N
    float* ee1  = ad2  + N_NODES;                       // ET*8
    float* ee2  = ee1  + (size_t)ET * H1;               // ET
    int* iw   = (int*)(ee2 + ET);
    int* cnt  = iw;                                     // N
    int* fill = cnt  + N_NODES;                         // N
    int* basep= fill + N_NODES;                         // N+1
    int* aux  = basep + N_NODES + 1;                    // 64
    int* auxs = aux  + 64;                              // 64
    int* srcs = auxs + 64;                              // ET
    int* dsts = srcs + ET;                              // ET
    uintptr_t pa = ((uintptr_t)(dsts + ET) + 255) & ~(uintptr_t)255;
    __bf16* Wp  = (__bf16*)pa;                          // 64K bf16 = 128KB
    __bf16* h1b = Wp + (size_t)FIN * D1;                // N*128 bf16
    __bf16* h2b = h1b + (size_t)N_NODES * D1;           // N*64 bf16

    const int gE = (ET + 255) / 256;

    k_zero   <<<(N_NODES + 255) / 256, 256, 0, stream>>>(cnt, fill);
    k_hist   <<<gE, 256, 0, stream>>>(ei, E, cnt);
    k_scan1  <<<NSCB, 256, 0, stream>>>(cnt, basep, aux);
    k_scan2  <<<1, 64, 0, stream>>>(aux, auxs);
    k_scan3  <<<(N_NODES + 255) / 256, 256, 0, stream>>>(basep, auxs, ET);
    k_scatter<<<gE, 256, 0, stream>>>(ei, E, basep, fill, srcs, dsts);

    k_cvtW   <<<FIN * D1 / 256, 256, 0, stream>>>(W1, Wp);
    k_gemm1  <<<(N_NODES + 63) / 64, 256, 0, stream>>>(x, Wp, h1b);
    k_att1   <<<(N_NODES * H1 + 255) / 256, 256, 0, stream>>>(h1b, asrc1, adst1, as1, ad1);
    k_edge1  <<<gE, 256, 0, stream>>>(srcs, dsts, as1, ad1, ee1, ET);
    k_agg1   <<<N_NODES / 4, 256, 0, stream>>>(basep, srcs, ee1, h1b, b1, out1);
    k_gemm2  <<<N_NODES / 4, 256, 0, stream>>>(out1, W2, asrc2, adst2, h2b, as2, ad2);
    k_edge2  <<<gE, 256, 0, stream>>>(srcs, dsts, as2, ad2, ee2, ET);
    k_agg2   <<<N_NODES / 4, 256, 0, stream>>>(basep, srcs, ee2, h2b, b2, (float*)d_out);
}

// Round 6
// 235.020 us; speedup vs baseline: 12.0498x; 1.1260x over previous
//
#include <hip/hip_runtime.h>
#include <math.h>

#define N_NODES 50000
#define FIN 512
#define H1 8
#define D1 128   // H1*C1
#define D2 64
#define NSCB ((N_NODES + 1023) >> 10)   // 49 scan blocks

typedef __attribute__((ext_vector_type(4))) float f32x4;
typedef __attribute__((ext_vector_type(8))) __bf16 bf16x8;
typedef __attribute__((ext_vector_type(4))) __bf16 bf16x4;
typedef __attribute__((ext_vector_type(2))) __bf16 bf16x2;

// ---------------- zero histogram counters --------------------------------
__global__ __launch_bounds__(256) void k_zero(int* __restrict__ cnt) {
    int i = blockIdx.x * 256 + threadIdx.x;
    if (i < N_NODES) cnt[i] = 0;
}

// ------- histogram of dst; also record each edge's within-segment rank ----
__global__ __launch_bounds__(256) void k_hist(const int* __restrict__ ei, int E,
                                              int* __restrict__ cnt,
                                              int* __restrict__ rank) {
    int e = blockIdx.x * 256 + threadIdx.x;
    int ET = E + N_NODES;
    if (e >= ET) return;
    int d = (e < E) ? ei[E + e] : (e - E);
    rank[e] = atomicAdd(&cnt[d], 1);
}

// ---------------- scan stage 1: per-block exclusive scan of cnt ----------
__global__ __launch_bounds__(256) void k_scan1(const int* __restrict__ cnt,
                                               int* __restrict__ basep,
                                               int* __restrict__ aux) {
    __shared__ int lds[256];
    int t = threadIdx.x, b = blockIdx.x;
    int g = b * 1024 + t * 4;
    int v0 = (g + 0 < N_NODES) ? cnt[g + 0] : 0;
    int v1 = (g + 1 < N_NODES) ? cnt[g + 1] : 0;
    int v2 = (g + 2 < N_NODES) ? cnt[g + 2] : 0;
    int v3 = (g + 3 < N_NODES) ? cnt[g + 3] : 0;
    int tsum = v0 + v1 + v2 + v3;
    lds[t] = tsum; __syncthreads();
    for (int off = 1; off < 256; off <<= 1) {
        int add = (t >= off) ? lds[t - off] : 0;
        __syncthreads();
        lds[t] += add;
        __syncthreads();
    }
    int excl = lds[t] - tsum;
    if (g + 0 < N_NODES) basep[g + 0] = excl;
    if (g + 1 < N_NODES) basep[g + 1] = excl + v0;
    if (g + 2 < N_NODES) basep[g + 2] = excl + v0 + v1;
    if (g + 3 < N_NODES) basep[g + 3] = excl + v0 + v1 + v2;
    if (t == 255) aux[b] = lds[255];
}

// ---------------- scan stage 2: scan the 49 block sums (one wave) --------
__global__ __launch_bounds__(64) void k_scan2(const int* __restrict__ aux,
                                              int* __restrict__ auxs) {
    int t = threadIdx.x;
    int v = (t < NSCB) ? aux[t] : 0;
    int orig = v;
    for (int off = 1; off < 64; off <<= 1) {
        int x = __shfl_up(v, off, 64);
        if (t >= off) v += x;
    }
    auxs[t] = v - orig;
}

// ---------------- scan stage 3: add block offsets ------------------------
__global__ __launch_bounds__(256) void k_scan3(int* __restrict__ basep,
                                               const int* __restrict__ auxs, int ET) {
    int i = blockIdx.x * 256 + threadIdx.x;
    if (i < N_NODES) basep[i] += auxs[i >> 10];
    if (i == 0) basep[N_NODES] = ET;
}

// ---------------- expand: dsts[basep[n]..basep[n+1]) = n (sequential) -----
__global__ __launch_bounds__(256) void k_expand(const int* __restrict__ basep,
                                                int* __restrict__ dsts) {
    int n = blockIdx.x * 256 + threadIdx.x;
    if (n >= N_NODES) return;
    int p0 = basep[n], p1 = basep[n + 1];
    for (int p = p0; p < p1; ++p) dsts[p] = n;
}

// ------- scatter srcs into dst-sorted order (no atomics) ------------------
__global__ __launch_bounds__(256) void k_scatter(const int* __restrict__ ei, int E,
                                                 const int* __restrict__ basep,
                                                 const int* __restrict__ rank,
                                                 int* __restrict__ srcs) {
    int e = blockIdx.x * 256 + threadIdx.x;
    int ET = E + N_NODES;
    if (e >= ET) return;
    int s = (e < E) ? ei[e] : (e - E);
    int d = (e < E) ? ei[E + e] : (e - E);
    srcs[basep[d] + rank[e]] = s;
}

// ---------------- W1 f32 -> bf16, fragment-packed: Wp[k>>3][col][k&7] ----
__global__ __launch_bounds__(256) void k_cvtW(const float* __restrict__ W1,
                                              __bf16* __restrict__ Wp) {
    int idx = blockIdx.x * 256 + threadIdx.x;   // 65536 = 512*128
    int k = idx >> 7, col = idx & 127;
    Wp[(k >> 3) * 1024 + col * 8 + (k & 7)] = (__bf16)W1[idx];
}

// ---------------- GEMM1 (MFMA): h1b[50000,128] bf16 = x @ W1 -------------
// block tile 64x128, 4 waves in 2x2, KB=64 per step, 8 steps
__global__ __launch_bounds__(256) void k_gemm1(const float* __restrict__ x,
                                               const __bf16* __restrict__ Wp,
                                               __bf16* __restrict__ h1b) {
    __shared__ __align__(16) __bf16 As[64 * 64];    // [row][k], XOR-swizzled
    __shared__ __align__(16) __bf16 Bs[64 * 128];   // [kgrp][col][8k], col^kgrp swz
    const int t = threadIdx.x;
    const int l = t & 63;
    const int w = t >> 6;
    const int wr = (w >> 1) * 32, wc = (w & 1) * 64;
    const int n0 = blockIdx.x * 64;

    f32x4 acc[2][4];
    #pragma unroll
    for (int i = 0; i < 2; ++i)
        #pragma unroll
        for (int j = 0; j < 4; ++j) acc[i][j] = (f32x4){0.f, 0.f, 0.f, 0.f};

    const int arow = t >> 4;            // staging row base (0..15)
    const int ak4  = (t & 15) * 4;      // staging k offset (elements)

    for (int s = 0; s < 8; ++s) {
        const int k0 = s * 64;
        // --- stage A: x[n0..n0+64][k0..k0+64] f32 -> bf16, swizzled ---
        #pragma unroll
        for (int i = 0; i < 4; ++i) {
            int row = arow + i * 16;
            int grow = n0 + row;
            float4 f = {0.f, 0.f, 0.f, 0.f};
            if (grow < N_NODES)
                f = *(const float4*)(x + (size_t)grow * FIN + k0 + ak4);
            bf16x4 v = {(__bf16)f.x, (__bf16)f.y, (__bf16)f.z, (__bf16)f.w};
            int eo = (row * 64 + ak4) ^ ((row & 7) << 3);
            *(bf16x4*)(As + eo) = v;
        }
        // --- stage B: linear 16KB copy of packed Wp, col^kgrp swizzle ---
        const uint4* gb = (const uint4*)(Wp + k0 * 128);
        #pragma unroll
        for (int i = 0; i < 4; ++i) {
            int u = t + i * 256;                 // 16B unit: kgrp=u>>7, col=u&127
            uint4 d = gb[u];
            int u2 = u ^ ((u >> 7) & 3);
            *(uint4*)(Bs + u2 * 8) = d;
        }
        __syncthreads();
        // --- MFMA: 2 k-substeps x 2 m-frags x 4 n-frags ---
        #pragma unroll
        for (int ks = 0; ks < 2; ++ks) {
            bf16x8 af[2], bf[4];
            #pragma unroll
            for (int fm = 0; fm < 2; ++fm) {
                int row = wr + fm * 16 + (l & 15);
                int eo = (row * 64 + ks * 32 + (l >> 4) * 8) ^ ((row & 7) << 3);
                af[fm] = *(const bf16x8*)(As + eo);
            }
            #pragma unroll
            for (int fn = 0; fn < 4; ++fn) {
                int col = wc + fn * 16 + (l & 15);
                int kg = ks * 4 + (l >> 4);
                int u = (kg * 128 + col) ^ (kg & 3);
                bf[fn] = *(const bf16x8*)(Bs + u * 8);
            }
            #pragma unroll
            for (int fm = 0; fm < 2; ++fm)
                #pragma unroll
                for (int fn = 0; fn < 4; ++fn)
                    acc[fm][fn] = __builtin_amdgcn_mfma_f32_16x16x32_bf16(
                        af[fm], bf[fn], acc[fm][fn], 0, 0, 0);
        }
        __syncthreads();
    }
    // --- epilogue: C[row][col] -> bf16, row=(l>>4)*4+reg, col=l&15 ---
    #pragma unroll
    for (int fm = 0; fm < 2; ++fm) {
        #pragma unroll
        for (int reg = 0; reg < 4; ++reg) {
            int row = n0 + wr + fm * 16 + (l >> 4) * 4 + reg;
            if (row >= N_NODES) continue;
            #pragma unroll
            for (int fn = 0; fn < 4; ++fn) {
                int col = wc + fn * 16 + (l & 15);
                h1b[(size_t)row * D1 + col] = (__bf16)acc[fm][fn][reg];
            }
        }
    }
}

// ---------------- attention dots layer 1 (bf16 h1) ------------------------
__global__ __launch_bounds__(256) void k_att1(const __bf16* __restrict__ h1b,
                                              const float* __restrict__ asrc,
                                              const float* __restrict__ adst,
                                              float* __restrict__ as1,
                                              float* __restrict__ ad1) {
    int idx = blockIdx.x * 256 + threadIdx.x;     // n*8+h
    if (idx >= N_NODES * H1) return;
    int h = idx & 7;
    const bf16x8* hv = (const bf16x8*)(h1b + (size_t)idx * 16);
    bf16x8 ha = hv[0], hb = hv[1];
    float hs[16];
    #pragma unroll
    for (int i = 0; i < 8; ++i) { hs[i] = (float)ha[i]; hs[8 + i] = (float)hb[i]; }
    const float* av = asrc + h * 16;
    const float* dv = adst + h * 16;
    float ss = 0.f, sd = 0.f;
    #pragma unroll
    for (int i = 0; i < 16; ++i) { ss += hs[i] * av[i]; sd += hs[i] * dv[i]; }
    as1[idx] = ss; ad1[idx] = sd;
}

// ------- edge pass 1: lane per edge, ee1[p][8] = exp(leaky(as+ad)) --------
__global__ __launch_bounds__(256) void k_edge1(const int* __restrict__ srcs,
                                               const int* __restrict__ dsts,
                                               const float* __restrict__ as1,
                                               const float* __restrict__ ad1,
                                               float* __restrict__ ee1, int ET) {
    int p = blockIdx.x * 256 + threadIdx.x;
    if (p >= ET) return;
    int s = srcs[p], d = dsts[p];
    const float4* av = (const float4*)(as1 + (size_t)s * 8);
    const float4* dv = (const float4*)(ad1 + (size_t)d * 8);
    float4 a0 = av[0], a1 = av[1], b0 = dv[0], b1 = dv[1];
    float u[8] = {a0.x + b0.x, a0.y + b0.y, a0.z + b0.z, a0.w + b0.w,
                  a1.x + b1.x, a1.y + b1.y, a1.z + b1.z, a1.w + b1.w};
    float ee[8];
    #pragma unroll
    for (int h = 0; h < 8; ++h) {
        float v = u[h];
        v = (v > 0.f) ? v : 0.2f * v;
        ee[h] = __expf(v);
    }
    float4* eo = (float4*)(ee1 + (size_t)p * 8);
    eo[0] = make_float4(ee[0], ee[1], ee[2], ee[3]);
    eo[1] = make_float4(ee[4], ee[5], ee[6], ee[7]);
}

// ------- aggregation layer 1: wave/node, 2 edges/iter, 4ch/lane -----------
__global__ __launch_bounds__(256) void k_agg1(const int* __restrict__ basep,
                                              const int* __restrict__ srcs,
                                              const float* __restrict__ ee1,
                                              const __bf16* __restrict__ h1b,
                                              const float* __restrict__ b1,
                                              float* __restrict__ out1) {
    const int w = threadIdx.x >> 6;
    const int l = threadIdx.x & 63;
    const int half = l >> 5;                   // which edge of the pair
    const int c4 = (l & 31) * 4;               // 4 channels per lane
    const int h = c4 >> 4;                     // head of this channel group
    const int n = blockIdx.x * 4 + w;          // 12500 blocks exactly
    const int p0 = basep[n], p1 = basep[n + 1];
    float a0 = 0.f, a1 = 0.f, a2 = 0.f, a3 = 0.f, se = 0.f;
    const int m = p1 - p0;
    #pragma unroll 2
    for (int j2 = 0; j2 < m; j2 += 2) {
        int j = j2 + half;
        bool ok = j < m;
        int p = p0 + (ok ? j : 0);
        int s = srcs[p];
        float ee = ee1[(size_t)p * 8 + h];
        if (!ok) ee = 0.f;
        se += ee;
        bf16x4 hv = *(const bf16x4*)(h1b + (size_t)s * D1 + c4);
        a0 += ee * (float)hv.x;
        a1 += ee * (float)hv.y;
        a2 += ee * (float)hv.z;
        a3 += ee * (float)hv.w;
    }
    a0 += __shfl_xor(a0, 32, 64);
    a1 += __shfl_xor(a1, 32, 64);
    a2 += __shfl_xor(a2, 32, 64);
    a3 += __shfl_xor(a3, 32, 64);
    se += __shfl_xor(se, 32, 64);
    if (half == 0) {
        float inv = 1.f / (se + 1e-16f);
        float4 r = {a0 * inv + b1[c4], a1 * inv + b1[c4 + 1],
                    a2 * inv + b1[c4 + 2], a3 * inv + b1[c4 + 3]};
        *(float4*)(out1 + (size_t)n * D1 + c4) = r;
    }
}

// ------- GEMM2 (+ReLU on load) + attention dots layer 2, bf16 h2 out ------
__global__ __launch_bounds__(256) void k_gemm2(const float* __restrict__ out1,
                                               const float* __restrict__ W2,
                                               const float* __restrict__ av2,
                                               const float* __restrict__ dv2,
                                               __bf16* __restrict__ h2b,
                                               float* __restrict__ as2,
                                               float* __restrict__ ad2) {
    __shared__ float rs[4 * D1];
    const int t = threadIdx.x;
    const int n0 = blockIdx.x * 4;
    #pragma unroll
    for (int i = t; i < 4 * D1; i += 256)
        rs[i] = fmaxf(out1[(size_t)n0 * D1 + i], 0.f);
    __syncthreads();
    const int w = t >> 6;
    const int c = t & 63;
    const int n = n0 + w;
    const float* r = rs + w * D1;
    float acc = 0.f;
    #pragma unroll 8
    for (int k = 0; k < D1; ++k) acc += r[k] * W2[(size_t)k * D2 + c];
    h2b[(size_t)n * D2 + c] = (__bf16)acc;
    float ps = acc * av2[c];
    float pd = acc * dv2[c];
    #pragma unroll
    for (int m = 32; m; m >>= 1) { ps += __shfl_xor(ps, m, 64); pd += __shfl_xor(pd, m, 64); }
    if (c == 0) { as2[n] = ps; ad2[n] = pd; }
}

// ------- edge pass 2: lane per edge, ee2[p] -------------------------------
__global__ __launch_bounds__(256) void k_edge2(const int* __restrict__ srcs,
                                               const int* __restrict__ dsts,
                                               const float* __restrict__ as2,
                                               const float* __restrict__ ad2,
                                               float* __restrict__ ee2, int ET) {
    int p = blockIdx.x * 256 + threadIdx.x;
    if (p >= ET) return;
    float u = as2[srcs[p]] + ad2[dsts[p]];
    u = (u > 0.f) ? u : 0.2f * u;
    ee2[p] = __expf(u);
}

// ------- aggregation layer 2 + bias + log_softmax, 4 edges/iter -----------
__global__ __launch_bounds__(256) void k_agg2(const int* __restrict__ basep,
                                              const int* __restrict__ srcs,
                                              const float* __restrict__ ee2,
                                              const __bf16* __restrict__ h2b,
                                              const float* __restrict__ b2,
                                              float* __restrict__ out) {
    const int w = threadIdx.x >> 6;
    const int l = threadIdx.x & 63;
    const int q = l >> 4;                      // edge slot within quad
    const int c4 = (l & 15) * 4;               // 4 channels per lane
    const int n = blockIdx.x * 4 + w;          // 12500 blocks exactly
    const int p0 = basep[n], p1 = basep[n + 1];
    float a0 = 0.f, a1 = 0.f, a2 = 0.f, a3 = 0.f, se = 0.f;
    const int m = p1 - p0;
    #pragma unroll 2
    for (int j4 = 0; j4 < m; j4 += 4) {
        int j = j4 + q;
        bool ok = j < m;
        int p = p0 + (ok ? j : 0);
        int s = srcs[p];
        float ee = ee2[p];
        if (!ok) ee = 0.f;
        se += ee;
        bf16x4 hv = *(const bf16x4*)(h2b + (size_t)s * D2 + c4);
        a0 += ee * (float)hv.x;
        a1 += ee * (float)hv.y;
        a2 += ee * (float)hv.z;
        a3 += ee * (float)hv.w;
    }
    #pragma unroll
    for (int mk = 16; mk <= 32; mk <<= 1) {
        a0 += __shfl_xor(a0, mk, 64);
        a1 += __shfl_xor(a1, mk, 64);
        a2 += __shfl_xor(a2, mk, 64);
        a3 += __shfl_xor(a3, mk, 64);
        se += __shfl_xor(se, mk, 64);
    }
    float inv = 1.f / (se + 1e-16f);
    float v0 = a0 * inv + b2[c4];
    float v1 = a1 * inv + b2[c4 + 1];
    float v2 = a2 * inv + b2[c4 + 2];
    float v3 = a3 * inv + b2[c4 + 3];
    // log_softmax over 64 channels (held by 16 lanes, duplicated in quads)
    float mx = fmaxf(fmaxf(v0, v1), fmaxf(v2, v3));
    #pragma unroll
    for (int mk = 1; mk <= 8; mk <<= 1) mx = fmaxf(mx, __shfl_xor(mx, mk, 64));
    float ex = __expf(v0 - mx) + __expf(v1 - mx) + __expf(v2 - mx) + __expf(v3 - mx);
    #pragma unroll
    for (int mk = 1; mk <= 8; mk <<= 1) ex += __shfl_xor(ex, mk, 64);
    float lse = mx + __logf(ex);
    if (q == 0) {
        float4 r = {v0 - lse, v1 - lse, v2 - lse, v3 - lse};
        *(float4*)(out + (size_t)n * D2 + c4) = r;
    }
}

extern "C" void kernel_launch(void* const* d_in, const int* in_sizes, int n_in,
                              void* d_out, int out_size, void* d_ws, size_t ws_size,
                              hipStream_t stream) {
    const float* x     = (const float*)d_in[0];
    const int*   ei    = (const int*)d_in[1];
    const float* W1    = (const float*)d_in[2];
    const float* asrc1 = (const float*)d_in[3];
    const float* adst1 = (const float*)d_in[4];
    const float* b1    = (const float*)d_in[5];
    const float* W2    = (const float*)d_in[6];
    const float* asrc2 = (const float*)d_in[7];
    const float* adst2 = (const float*)d_in[8];
    const float* b2    = (const float*)d_in[9];

    const int E  = in_sizes[1] / 2;   // 800000
    const int ET = E + N_NODES;       // 850000

    // ---- workspace layout ----
    float* fw = (float*)d_ws;
    float* out1 = fw;                                   // N*128
    float* as1  = out1 + (size_t)N_NODES * D1;          // N*8
    float* ad1  = as1  + (size_t)N_NODES * H1;          // N*8
    float* as2  = ad1  + (size_t)N_NODES * H1;          // N
    float* ad2  = as2  + N_NODES;                       // N
    float* ee1  = ad2  + N_NODES;                       // ET*8
    float* ee2  = ee1  + (size_t)ET * H1;               // ET
    int* iw   = (int*)(ee2 + ET);
    int* cnt  = iw;                                     // N
    int* basep= cnt  + N_NODES;                         // N+1
    int* aux  = basep + N_NODES + 1;                    // 64
    int* auxs = aux  + 64;                              // 64
    int* rank = auxs + 64;                              // ET
    int* srcs = rank + ET;                              // ET
    int* dsts = srcs + ET;                              // ET
    uintptr_t pa = ((uintptr_t)(dsts + ET) + 255) & ~(uintptr_t)255;
    __bf16* Wp  = (__bf16*)pa;                          // 64K bf16 = 128KB
    __bf16* h1b = Wp + (size_t)FIN * D1;                // N*128 bf16
    __bf16* h2b = h1b + (size_t)N_NODES * D1;           // N*64 bf16

    const int gE = (ET + 255) / 256;
    const int gN = (N_NODES + 255) / 256;

    k_zero   <<<gN, 256, 0, stream>>>(cnt);
    k_hist   <<<gE, 256, 0, stream>>>(ei, E, cnt, rank);
    k_scan1  <<<NSCB, 256, 0, stream>>>(cnt, basep, aux);
    k_scan2  <<<1, 64, 0, stream>>>(aux, auxs);
    k_scan3  <<<gN, 256, 0, stream>>>(basep, auxs, ET);
    k_expand <<<gN, 256, 0, stream>>>(basep, dsts);
    k_scatter<<<gE, 256, 0, stream>>>(ei, E, basep, rank, srcs);

    k_cvtW   <<<FIN * D1 / 256, 256, 0, stream>>>(W1, Wp);
    k_gemm1  <<<(N_NODES + 63) / 64, 256, 0, stream>>>(x, Wp, h1b);
    k_att1   <<<(N_NODES * H1 + 255) / 256, 256, 0, stream>>>(h1b, asrc1, adst1, as1, ad1);
    k_edge1  <<<gE, 256, 0, stream>>>(srcs, dsts, as1, ad1, ee1, ET);
    k_agg1   <<<N_NODES / 4, 256, 0, stream>>>(basep, srcs, ee1, h1b, b1, out1);
    k_gemm2  <<<N_NODES / 4, 256, 0, stream>>>(out1, W2, asrc2, adst2, h2b, as2, ad2);
    k_edge2  <<<gE, 256, 0, stream>>>(srcs, dsts, as2, ad2, ee2, ET);
    k_agg2   <<<N_NODES / 4, 256, 0, stream>>>(basep, srcs, ee2, h2b, b2, (float*)d_out);
}

// Round 7
// 194.499 us; speedup vs baseline: 14.5602x; 1.2083x over previous
//
#include <hip/hip_runtime.h>
#include <math.h>

#define N_NODES 50000
#define FIN 512
#define H1 8
#define D1 128   // H1*C1
#define D2 64
#define NSCB ((N_NODES + 1023) >> 10)   // 49 scan blocks

typedef __attribute__((ext_vector_type(4))) float f32x4;
typedef __attribute__((ext_vector_type(8))) __bf16 bf16x8;
typedef __attribute__((ext_vector_type(4))) __bf16 bf16x4;
typedef __attribute__((ext_vector_type(2))) __bf16 bf16x2;

// ---------------- zero histogram counters --------------------------------
__global__ __launch_bounds__(256) void k_zero(int* __restrict__ cnt) {
    int i = blockIdx.x * 256 + threadIdx.x;
    if (i < N_NODES) cnt[i] = 0;
}

// ------- histogram of dst; also record each edge's within-segment rank ----
__global__ __launch_bounds__(256) void k_hist(const int* __restrict__ ei, int E,
                                              int* __restrict__ cnt,
                                              int* __restrict__ rank) {
    int e = blockIdx.x * 256 + threadIdx.x;
    int ET = E + N_NODES;
    if (e >= ET) return;
    int d = (e < E) ? ei[E + e] : (e - E);
    rank[e] = atomicAdd(&cnt[d], 1);
}

// ---------------- scan stage 1: per-block exclusive scan of cnt ----------
__global__ __launch_bounds__(256) void k_scan1(const int* __restrict__ cnt,
                                               int* __restrict__ basep,
                                               int* __restrict__ aux) {
    __shared__ int lds[256];
    int t = threadIdx.x, b = blockIdx.x;
    int g = b * 1024 + t * 4;
    int v0 = (g + 0 < N_NODES) ? cnt[g + 0] : 0;
    int v1 = (g + 1 < N_NODES) ? cnt[g + 1] : 0;
    int v2 = (g + 2 < N_NODES) ? cnt[g + 2] : 0;
    int v3 = (g + 3 < N_NODES) ? cnt[g + 3] : 0;
    int tsum = v0 + v1 + v2 + v3;
    lds[t] = tsum; __syncthreads();
    for (int off = 1; off < 256; off <<= 1) {
        int add = (t >= off) ? lds[t - off] : 0;
        __syncthreads();
        lds[t] += add;
        __syncthreads();
    }
    int excl = lds[t] - tsum;
    if (g + 0 < N_NODES) basep[g + 0] = excl;
    if (g + 1 < N_NODES) basep[g + 1] = excl + v0;
    if (g + 2 < N_NODES) basep[g + 2] = excl + v0 + v1;
    if (g + 3 < N_NODES) basep[g + 3] = excl + v0 + v1 + v2;
    if (t == 255) aux[b] = lds[255];
}

// ---------------- scan stage 2: scan the 49 block sums (one wave) --------
__global__ __launch_bounds__(64) void k_scan2(const int* __restrict__ aux,
                                              int* __restrict__ auxs) {
    int t = threadIdx.x;
    int v = (t < NSCB) ? aux[t] : 0;
    int orig = v;
    for (int off = 1; off < 64; off <<= 1) {
        int x = __shfl_up(v, off, 64);
        if (t >= off) v += x;
    }
    auxs[t] = v - orig;
}

// ---------------- scan stage 3: add block offsets ------------------------
__global__ __launch_bounds__(256) void k_scan3(int* __restrict__ basep,
                                               const int* __restrict__ auxs, int ET) {
    int i = blockIdx.x * 256 + threadIdx.x;
    if (i < N_NODES) basep[i] += auxs[i >> 10];
    if (i == 0) basep[N_NODES] = ET;
}

// ---------------- expand: dsts[basep[n]..basep[n+1]) = n (sequential) -----
__global__ __launch_bounds__(256) void k_expand(const int* __restrict__ basep,
                                                int* __restrict__ dsts) {
    int n = blockIdx.x * 256 + threadIdx.x;
    if (n >= N_NODES) return;
    int p0 = basep[n], p1 = basep[n + 1];
    for (int p = p0; p < p1; ++p) dsts[p] = n;
}

// ------- scatter srcs into dst-sorted order (no atomics) ------------------
__global__ __launch_bounds__(256) void k_scatter(const int* __restrict__ ei, int E,
                                                 const int* __restrict__ basep,
                                                 const int* __restrict__ rank,
                                                 int* __restrict__ srcs) {
    int e = blockIdx.x * 256 + threadIdx.x;
    int ET = E + N_NODES;
    if (e >= ET) return;
    int s = (e < E) ? ei[e] : (e - E);
    int d = (e < E) ? ei[E + e] : (e - E);
    srcs[basep[d] + rank[e]] = s;
}

// ---------------- W1 f32 -> bf16, fragment-packed: Wp[k>>3][col][k&7] ----
__global__ __launch_bounds__(256) void k_cvtW(const float* __restrict__ W1,
                                              __bf16* __restrict__ Wp) {
    int idx = blockIdx.x * 256 + threadIdx.x;   // 65536 = 512*128
    int k = idx >> 7, col = idx & 127;
    Wp[(k >> 3) * 1024 + col * 8 + (k & 7)] = (__bf16)W1[idx];
}

// ---------------- W2 f32 -> bf16, fragment-packed: Wp2[k>>3][col][k&7] ---
__global__ __launch_bounds__(256) void k_cvtW2(const float* __restrict__ W2,
                                               __bf16* __restrict__ Wp2) {
    int idx = blockIdx.x * 256 + threadIdx.x;   // 8192 = 128*64
    if (idx >= D1 * D2) return;
    int k = idx >> 6, col = idx & 63;
    Wp2[(k >> 3) * 512 + col * 8 + (k & 7)] = (__bf16)W2[idx];
}

// ---------------- GEMM1 (MFMA): h1b[50000,128] bf16 = x @ W1 -------------
// block tile 64x128, 4 waves in 2x2, KB=64 per step, 8 steps
__global__ __launch_bounds__(256) void k_gemm1(const float* __restrict__ x,
                                               const __bf16* __restrict__ Wp,
                                               __bf16* __restrict__ h1b) {
    __shared__ __align__(16) __bf16 As[64 * 64];    // [row][k], XOR-swizzled
    __shared__ __align__(16) __bf16 Bs[64 * 128];   // [kgrp][col][8k], col^kgrp swz
    const int t = threadIdx.x;
    const int l = t & 63;
    const int w = t >> 6;
    const int wr = (w >> 1) * 32, wc = (w & 1) * 64;
    const int n0 = blockIdx.x * 64;

    f32x4 acc[2][4];
    #pragma unroll
    for (int i = 0; i < 2; ++i)
        #pragma unroll
        for (int j = 0; j < 4; ++j) acc[i][j] = (f32x4){0.f, 0.f, 0.f, 0.f};

    const int arow = t >> 4;            // staging row base (0..15)
    const int ak4  = (t & 15) * 4;      // staging k offset (elements)

    for (int s = 0; s < 8; ++s) {
        const int k0 = s * 64;
        // --- stage A: x[n0..n0+64][k0..k0+64] f32 -> bf16, swizzled ---
        #pragma unroll
        for (int i = 0; i < 4; ++i) {
            int row = arow + i * 16;
            int grow = n0 + row;
            float4 f = {0.f, 0.f, 0.f, 0.f};
            if (grow < N_NODES)
                f = *(const float4*)(x + (size_t)grow * FIN + k0 + ak4);
            bf16x4 v = {(__bf16)f.x, (__bf16)f.y, (__bf16)f.z, (__bf16)f.w};
            int eo = (row * 64 + ak4) ^ ((row & 7) << 3);
            *(bf16x4*)(As + eo) = v;
        }
        // --- stage B: linear 16KB copy of packed Wp, col^kgrp swizzle ---
        const uint4* gb = (const uint4*)(Wp + k0 * 128);
        #pragma unroll
        for (int i = 0; i < 4; ++i) {
            int u = t + i * 256;                 // 16B unit: kgrp=u>>7, col=u&127
            uint4 d = gb[u];
            int u2 = u ^ ((u >> 7) & 3);
            *(uint4*)(Bs + u2 * 8) = d;
        }
        __syncthreads();
        // --- MFMA: 2 k-substeps x 2 m-frags x 4 n-frags ---
        #pragma unroll
        for (int ks = 0; ks < 2; ++ks) {
            bf16x8 af[2], bf[4];
            #pragma unroll
            for (int fm = 0; fm < 2; ++fm) {
                int row = wr + fm * 16 + (l & 15);
                int eo = (row * 64 + ks * 32 + (l >> 4) * 8) ^ ((row & 7) << 3);
                af[fm] = *(const bf16x8*)(As + eo);
            }
            #pragma unroll
            for (int fn = 0; fn < 4; ++fn) {
                int col = wc + fn * 16 + (l & 15);
                int kg = ks * 4 + (l >> 4);
                int u = (kg * 128 + col) ^ (kg & 3);
                bf[fn] = *(const bf16x8*)(Bs + u * 8);
            }
            #pragma unroll
            for (int fm = 0; fm < 2; ++fm)
                #pragma unroll
                for (int fn = 0; fn < 4; ++fn)
                    acc[fm][fn] = __builtin_amdgcn_mfma_f32_16x16x32_bf16(
                        af[fm], bf[fn], acc[fm][fn], 0, 0, 0);
        }
        __syncthreads();
    }
    // --- epilogue: C[row][col] -> bf16, row=(l>>4)*4+reg, col=l&15 ---
    #pragma unroll
    for (int fm = 0; fm < 2; ++fm) {
        #pragma unroll
        for (int reg = 0; reg < 4; ++reg) {
            int row = n0 + wr + fm * 16 + (l >> 4) * 4 + reg;
            if (row >= N_NODES) continue;
            #pragma unroll
            for (int fn = 0; fn < 4; ++fn) {
                int col = wc + fn * 16 + (l & 15);
                h1b[(size_t)row * D1 + col] = (__bf16)acc[fm][fn][reg];
            }
        }
    }
}

// ---------------- attention dots layer 1 (bf16 h1) ------------------------
__global__ __launch_bounds__(256) void k_att1(const __bf16* __restrict__ h1b,
                                              const float* __restrict__ asrc,
                                              const float* __restrict__ adst,
                                              float* __restrict__ as1,
                                              float* __restrict__ ad1) {
    int idx = blockIdx.x * 256 + threadIdx.x;     // n*8+h
    if (idx >= N_NODES * H1) return;
    int h = idx & 7;
    const bf16x8* hv = (const bf16x8*)(h1b + (size_t)idx * 16);
    bf16x8 ha = hv[0], hb = hv[1];
    float hs[16];
    #pragma unroll
    for (int i = 0; i < 8; ++i) { hs[i] = (float)ha[i]; hs[8 + i] = (float)hb[i]; }
    const float* av = asrc + h * 16;
    const float* dv = adst + h * 16;
    float ss = 0.f, sd = 0.f;
    #pragma unroll
    for (int i = 0; i < 16; ++i) { ss += hs[i] * av[i]; sd += hs[i] * dv[i]; }
    as1[idx] = ss; ad1[idx] = sd;
}

// ------- edge pass 1: lane per edge, ee1[p][8] = exp(leaky(as+ad)) --------
__global__ __launch_bounds__(256) void k_edge1(const int* __restrict__ srcs,
                                               const int* __restrict__ dsts,
                                               const float* __restrict__ as1,
                                               const float* __restrict__ ad1,
                                               float* __restrict__ ee1, int ET) {
    int p = blockIdx.x * 256 + threadIdx.x;
    if (p >= ET) return;
    int s = srcs[p], d = dsts[p];
    const float4* av = (const float4*)(as1 + (size_t)s * 8);
    const float4* dv = (const float4*)(ad1 + (size_t)d * 8);
    float4 a0 = av[0], a1 = av[1], b0 = dv[0], b1 = dv[1];
    float u[8] = {a0.x + b0.x, a0.y + b0.y, a0.z + b0.z, a0.w + b0.w,
                  a1.x + b1.x, a1.y + b1.y, a1.z + b1.z, a1.w + b1.w};
    float ee[8];
    #pragma unroll
    for (int h = 0; h < 8; ++h) {
        float v = u[h];
        v = (v > 0.f) ? v : 0.2f * v;
        ee[h] = __expf(v);
    }
    float4* eo = (float4*)(ee1 + (size_t)p * 8);
    eo[0] = make_float4(ee[0], ee[1], ee[2], ee[3]);
    eo[1] = make_float4(ee[4], ee[5], ee[6], ee[7]);
}

// ------- aggregation layer 1: wave/node, 2 edges/iter, 4ch/lane -----------
// epilogue fuses +bias, ReLU, bf16 store (feeds MFMA GEMM2)
__global__ __launch_bounds__(256) void k_agg1(const int* __restrict__ basep,
                                              const int* __restrict__ srcs,
                                              const float* __restrict__ ee1,
                                              const __bf16* __restrict__ h1b,
                                              const float* __restrict__ b1,
                                              __bf16* __restrict__ r1b) {
    const int w = threadIdx.x >> 6;
    const int l = threadIdx.x & 63;
    const int half = l >> 5;                   // which edge of the pair
    const int c4 = (l & 31) * 4;               // 4 channels per lane
    const int h = c4 >> 4;                     // head of this channel group
    const int n = blockIdx.x * 4 + w;          // 12500 blocks exactly
    const int p0 = basep[n], p1 = basep[n + 1];
    float a0 = 0.f, a1 = 0.f, a2 = 0.f, a3 = 0.f, se = 0.f;
    const int m = p1 - p0;
    #pragma unroll 2
    for (int j2 = 0; j2 < m; j2 += 2) {
        int j = j2 + half;
        bool ok = j < m;
        int p = p0 + (ok ? j : 0);
        int s = srcs[p];
        float ee = ee1[(size_t)p * 8 + h];
        if (!ok) ee = 0.f;
        se += ee;
        bf16x4 hv = *(const bf16x4*)(h1b + (size_t)s * D1 + c4);
        a0 += ee * (float)hv.x;
        a1 += ee * (float)hv.y;
        a2 += ee * (float)hv.z;
        a3 += ee * (float)hv.w;
    }
    a0 += __shfl_xor(a0, 32, 64);
    a1 += __shfl_xor(a1, 32, 64);
    a2 += __shfl_xor(a2, 32, 64);
    a3 += __shfl_xor(a3, 32, 64);
    se += __shfl_xor(se, 32, 64);
    if (half == 0) {
        float inv = 1.f / (se + 1e-16f);
        bf16x4 r = {(__bf16)fmaxf(a0 * inv + b1[c4], 0.f),
                    (__bf16)fmaxf(a1 * inv + b1[c4 + 1], 0.f),
                    (__bf16)fmaxf(a2 * inv + b1[c4 + 2], 0.f),
                    (__bf16)fmaxf(a3 * inv + b1[c4 + 3], 0.f)};
        *(bf16x4*)(r1b + (size_t)n * D1 + c4) = r;
    }
}

// ------- GEMM2 (MFMA): h2b[50000,64] bf16 = r1b @ W2 ----------------------
// block tile 128x64, K=128 staged once, 4 waves each 32 rows x 64 cols
__global__ __launch_bounds__(256) void k_gemm2(const __bf16* __restrict__ r1b,
                                               const __bf16* __restrict__ Wp2,
                                               __bf16* __restrict__ h2b) {
    __shared__ __align__(16) __bf16 As[128 * 128];  // 32KB, XOR-swizzled
    __shared__ __align__(16) __bf16 Bs[128 * 64];   // 16KB, packed+swizzled
    const int t = threadIdx.x;
    const int l = t & 63;
    const int w = t >> 6;
    const int wr = w * 32;
    const int n0 = blockIdx.x * 128;

    // stage B: 1024 x 16B chunks (kg = u>>6, col = u&63)
    const uint4* gb = (const uint4*)Wp2;
    #pragma unroll
    for (int i = 0; i < 4; ++i) {
        int u = t + i * 256;
        uint4 d = gb[u];
        int u2 = u ^ ((u >> 6) & 3);
        *(uint4*)(Bs + u2 * 8) = d;
    }
    // stage A: 2048 x 16B chunks (row = u>>4, koff = (u&15)*8)
    #pragma unroll
    for (int i = 0; i < 8; ++i) {
        int u = t + i * 256;
        int row = u >> 4, koff = (u & 15) * 8;
        bf16x8 v = {};
        if (n0 + row < N_NODES)
            v = *(const bf16x8*)(r1b + (size_t)(n0 + row) * D1 + koff);
        int eo = (row * 128 + koff) ^ ((row & 7) << 3);
        *(bf16x8*)(As + eo) = v;
    }
    __syncthreads();

    f32x4 acc[2][4];
    #pragma unroll
    for (int i = 0; i < 2; ++i)
        #pragma unroll
        for (int j = 0; j < 4; ++j) acc[i][j] = (f32x4){0.f, 0.f, 0.f, 0.f};

    #pragma unroll
    for (int ks = 0; ks < 4; ++ks) {
        bf16x8 af[2], bfr[4];
        #pragma unroll
        for (int fm = 0; fm < 2; ++fm) {
            int row = wr + fm * 16 + (l & 15);
            int eo = (row * 128 + ks * 32 + (l >> 4) * 8) ^ ((row & 7) << 3);
            af[fm] = *(const bf16x8*)(As + eo);
        }
        #pragma unroll
        for (int fn = 0; fn < 4; ++fn) {
            int col = fn * 16 + (l & 15);
            int kg = ks * 4 + (l >> 4);
            int u = (kg * 64 + col) ^ (kg & 3);
            bfr[fn] = *(const bf16x8*)(Bs + u * 8);
        }
        #pragma unroll
        for (int fm = 0; fm < 2; ++fm)
            #pragma unroll
            for (int fn = 0; fn < 4; ++fn)
                acc[fm][fn] = __builtin_amdgcn_mfma_f32_16x16x32_bf16(
                    af[fm], bfr[fn], acc[fm][fn], 0, 0, 0);
    }
    // epilogue: store bf16 h2
    #pragma unroll
    for (int fm = 0; fm < 2; ++fm) {
        #pragma unroll
        for (int reg = 0; reg < 4; ++reg) {
            int row = n0 + wr + fm * 16 + (l >> 4) * 4 + reg;
            if (row >= N_NODES) continue;
            #pragma unroll
            for (int fn = 0; fn < 4; ++fn) {
                int col = fn * 16 + (l & 15);
                h2b[(size_t)row * D2 + col] = (__bf16)acc[fm][fn][reg];
            }
        }
    }
}

// ---------------- attention dots layer 2 (bf16 h2) ------------------------
__global__ __launch_bounds__(256) void k_att2(const __bf16* __restrict__ h2b,
                                              const float* __restrict__ av2,
                                              const float* __restrict__ dv2,
                                              float* __restrict__ as2,
                                              float* __restrict__ ad2) {
    int n = blockIdx.x * 256 + threadIdx.x;
    if (n >= N_NODES) return;
    const bf16x8* hv = (const bf16x8*)(h2b + (size_t)n * D2);
    float ss = 0.f, sd = 0.f;
    #pragma unroll
    for (int i = 0; i < 8; ++i) {
        bf16x8 h8 = hv[i];
        #pragma unroll
        for (int j = 0; j < 8; ++j) {
            float hf = (float)h8[j];
            ss += hf * av2[i * 8 + j];
            sd += hf * dv2[i * 8 + j];
        }
    }
    as2[n] = ss; ad2[n] = sd;
}

// ------- edge pass 2: lane per edge, ee2[p] -------------------------------
__global__ __launch_bounds__(256) void k_edge2(const int* __restrict__ srcs,
                                               const int* __restrict__ dsts,
                                               const float* __restrict__ as2,
                                               const float* __restrict__ ad2,
                                               float* __restrict__ ee2, int ET) {
    int p = blockIdx.x * 256 + threadIdx.x;
    if (p >= ET) return;
    float u = as2[srcs[p]] + ad2[dsts[p]];
    u = (u > 0.f) ? u : 0.2f * u;
    ee2[p] = __expf(u);
}

// ------- aggregation layer 2 + bias + log_softmax, 4 edges/iter -----------
__global__ __launch_bounds__(256) void k_agg2(const int* __restrict__ basep,
                                              const int* __restrict__ srcs,
                                              const float* __restrict__ ee2,
                                              const __bf16* __restrict__ h2b,
                                              const float* __restrict__ b2,
                                              float* __restrict__ out) {
    const int w = threadIdx.x >> 6;
    const int l = threadIdx.x & 63;
    const int q = l >> 4;                      // edge slot within quad
    const int c4 = (l & 15) * 4;               // 4 channels per lane
    const int n = blockIdx.x * 4 + w;          // 12500 blocks exactly
    const int p0 = basep[n], p1 = basep[n + 1];
    float a0 = 0.f, a1 = 0.f, a2 = 0.f, a3 = 0.f, se = 0.f;
    const int m = p1 - p0;
    #pragma unroll 2
    for (int j4 = 0; j4 < m; j4 += 4) {
        int j = j4 + q;
        bool ok = j < m;
        int p = p0 + (ok ? j : 0);
        int s = srcs[p];
        float ee = ee2[p];
        if (!ok) ee = 0.f;
        se += ee;
        bf16x4 hv = *(const bf16x4*)(h2b + (size_t)s * D2 + c4);
        a0 += ee * (float)hv.x;
        a1 += ee * (float)hv.y;
        a2 += ee * (float)hv.z;
        a3 += ee * (float)hv.w;
    }
    #pragma unroll
    for (int mk = 16; mk <= 32; mk <<= 1) {
        a0 += __shfl_xor(a0, mk, 64);
        a1 += __shfl_xor(a1, mk, 64);
        a2 += __shfl_xor(a2, mk, 64);
        a3 += __shfl_xor(a3, mk, 64);
        se += __shfl_xor(se, mk, 64);
    }
    float inv = 1.f / (se + 1e-16f);
    float v0 = a0 * inv + b2[c4];
    float v1 = a1 * inv + b2[c4 + 1];
    float v2 = a2 * inv + b2[c4 + 2];
    float v3 = a3 * inv + b2[c4 + 3];
    // log_softmax over 64 channels (held by 16 lanes, duplicated in quads)
    float mx = fmaxf(fmaxf(v0, v1), fmaxf(v2, v3));
    #pragma unroll
    for (int mk = 1; mk <= 8; mk <<= 1) mx = fmaxf(mx, __shfl_xor(mx, mk, 64));
    float ex = __expf(v0 - mx) + __expf(v1 - mx) + __expf(v2 - mx) + __expf(v3 - mx);
    #pragma unroll
    for (int mk = 1; mk <= 8; mk <<= 1) ex += __shfl_xor(ex, mk, 64);
    float lse = mx + __logf(ex);
    if (q == 0) {
        float4 r = {v0 - lse, v1 - lse, v2 - lse, v3 - lse};
        *(float4*)(out + (size_t)n * D2 + c4) = r;
    }
}

extern "C" void kernel_launch(void* const* d_in, const int* in_sizes, int n_in,
                              void* d_out, int out_size, void* d_ws, size_t ws_size,
                              hipStream_t stream) {
    const float* x     = (const float*)d_in[0];
    const int*   ei    = (const int*)d_in[1];
    const float* W1    = (const float*)d_in[2];
    const float* asrc1 = (const float*)d_in[3];
    const float* adst1 = (const float*)d_in[4];
    const float* b1    = (const float*)d_in[5];
    const float* W2    = (const float*)d_in[6];
    const float* asrc2 = (const float*)d_in[7];
    const float* adst2 = (const float*)d_in[8];
    const float* b2    = (const float*)d_in[9];

    const int E  = in_sizes[1] / 2;   // 800000
    const int ET = E + N_NODES;       // 850000

    // ---- workspace layout ----
    __bf16* r1b = (__bf16*)d_ws;                        // N*128 bf16 (relu1)
    float* fw  = (float*)(r1b + (size_t)N_NODES * D1);
    float* as1  = fw;                                   // N*8
    float* ad1  = as1  + (size_t)N_NODES * H1;          // N*8
    float* as2  = ad1  + (size_t)N_NODES * H1;          // N
    float* ad2  = as2  + N_NODES;                       // N
    float* ee1  = ad2  + N_NODES;                       // ET*8
    float* ee2  = ee1  + (size_t)ET * H1;               // ET
    int* iw   = (int*)(ee2 + ET);
    int* cnt  = iw;                                     // N
    int* basep= cnt  + N_NODES;                         // N+1
    int* aux  = basep + N_NODES + 1;                    // 64
    int* auxs = aux  + 64;                              // 64
    int* rank = auxs + 64;                              // ET
    int* srcs = rank + ET;                              // ET
    int* dsts = srcs + ET;                              // ET
    uintptr_t pa = ((uintptr_t)(dsts + ET) + 255) & ~(uintptr_t)255;
    __bf16* Wp   = (__bf16*)pa;                         // 512*128 bf16
    __bf16* Wp2  = Wp  + (size_t)FIN * D1;              // 128*64 bf16
    __bf16* h1b  = Wp2 + (size_t)D1 * D2;               // N*128 bf16
    __bf16* h2b  = h1b + (size_t)N_NODES * D1;          // N*64 bf16

    const int gE = (ET + 255) / 256;
    const int gN = (N_NODES + 255) / 256;

    k_zero   <<<gN, 256, 0, stream>>>(cnt);
    k_hist   <<<gE, 256, 0, stream>>>(ei, E, cnt, rank);
    k_scan1  <<<NSCB, 256, 0, stream>>>(cnt, basep, aux);
    k_scan2  <<<1, 64, 0, stream>>>(aux, auxs);
    k_scan3  <<<gN, 256, 0, stream>>>(basep, auxs, ET);
    k_expand <<<gN, 256, 0, stream>>>(basep, dsts);
    k_scatter<<<gE, 256, 0, stream>>>(ei, E, basep, rank, srcs);

    k_cvtW   <<<FIN * D1 / 256, 256, 0, stream>>>(W1, Wp);
    k_cvtW2  <<<(D1 * D2 + 255) / 256, 256, 0, stream>>>(W2, Wp2);
    k_gemm1  <<<(N_NODES + 63) / 64, 256, 0, stream>>>(x, Wp, h1b);
    k_att1   <<<(N_NODES * H1 + 255) / 256, 256, 0, stream>>>(h1b, asrc1, adst1, as1, ad1);
    k_edge1  <<<gE, 256, 0, stream>>>(srcs, dsts, as1, ad1, ee1, ET);
    k_agg1   <<<N_NODES / 4, 256, 0, stream>>>(basep, srcs, ee1, h1b, b1, r1b);
    k_gemm2  <<<(N_NODES + 127) / 128, 256, 0, stream>>>(r1b, Wp2, h2b);
    k_att2   <<<gN, 256, 0, stream>>>(h2b, asrc2, adst2, as2, ad2);
    k_edge2  <<<gE, 256, 0, stream>>>(srcs, dsts, as2, ad2, ee2, ET);
    k_agg2   <<<N_NODES / 4, 256, 0, stream>>>(basep, srcs, ee2, h2b, b2, (float*)d_out);
}

// Round 8
// 185.231 us; speedup vs baseline: 15.2887x; 1.0500x over previous
//
#include <hip/hip_runtime.h>
#include <math.h>

#define N_NODES 50000
#define FIN 512
#define H1 8
#define D1 128   // H1*C1
#define D2 64
#define NSCB ((N_NODES + 1023) >> 10)   // 49 scan blocks

typedef __attribute__((ext_vector_type(4))) float f32x4;
typedef __attribute__((ext_vector_type(8))) __bf16 bf16x8;
typedef __attribute__((ext_vector_type(4))) __bf16 bf16x4;

// ------- prep: zero cnt, pack W1 and W2 to bf16 fragment layout -----------
__global__ __launch_bounds__(256) void k_prep(const float* __restrict__ W1,
                                              const float* __restrict__ W2,
                                              __bf16* __restrict__ Wp,
                                              __bf16* __restrict__ Wp2,
                                              int* __restrict__ cnt) {
    int idx = blockIdx.x * 256 + threadIdx.x;   // 65536 = 512*128
    int k = idx >> 7, col = idx & 127;
    Wp[(k >> 3) * 1024 + col * 8 + (k & 7)] = (__bf16)W1[idx];
    if (idx < N_NODES) cnt[idx] = 0;
    if (idx < D1 * D2) {
        int k2 = idx >> 6, col2 = idx & 63;
        Wp2[(k2 >> 3) * 512 + col2 * 8 + (k2 & 7)] = (__bf16)W2[idx];
    }
}

// ------- histogram of dst; also record each edge's within-segment rank ----
__global__ __launch_bounds__(256) void k_hist(const int* __restrict__ ei, int E,
                                              int* __restrict__ cnt,
                                              int* __restrict__ rank) {
    int e = blockIdx.x * 256 + threadIdx.x;
    int ET = E + N_NODES;
    if (e >= ET) return;
    int d = (e < E) ? ei[E + e] : (e - E);
    rank[e] = atomicAdd(&cnt[d], 1);
}

// ---------------- scan stage 1: per-block exclusive scan of cnt ----------
__global__ __launch_bounds__(256) void k_scan1(const int* __restrict__ cnt,
                                               int* __restrict__ basep,
                                               int* __restrict__ aux) {
    __shared__ int lds[256];
    int t = threadIdx.x, b = blockIdx.x;
    int g = b * 1024 + t * 4;
    int v0 = (g + 0 < N_NODES) ? cnt[g + 0] : 0;
    int v1 = (g + 1 < N_NODES) ? cnt[g + 1] : 0;
    int v2 = (g + 2 < N_NODES) ? cnt[g + 2] : 0;
    int v3 = (g + 3 < N_NODES) ? cnt[g + 3] : 0;
    int tsum = v0 + v1 + v2 + v3;
    lds[t] = tsum; __syncthreads();
    for (int off = 1; off < 256; off <<= 1) {
        int add = (t >= off) ? lds[t - off] : 0;
        __syncthreads();
        lds[t] += add;
        __syncthreads();
    }
    int excl = lds[t] - tsum;
    if (g + 0 < N_NODES) basep[g + 0] = excl;
    if (g + 1 < N_NODES) basep[g + 1] = excl + v0;
    if (g + 2 < N_NODES) basep[g + 2] = excl + v0 + v1;
    if (g + 3 < N_NODES) basep[g + 3] = excl + v0 + v1 + v2;
    if (t == 255) aux[b] = lds[255];
}

// ---------------- scan stage 2: scan the 49 block sums (one wave) --------
__global__ __launch_bounds__(64) void k_scan2(const int* __restrict__ aux,
                                              int* __restrict__ auxs) {
    int t = threadIdx.x;
    int v = (t < NSCB) ? aux[t] : 0;
    int orig = v;
    for (int off = 1; off < 64; off <<= 1) {
        int x = __shfl_up(v, off, 64);
        if (t >= off) v += x;
    }
    auxs[t] = v - orig;
}

// ---------------- scan stage 3: add block offsets ------------------------
__global__ __launch_bounds__(256) void k_scan3(int* __restrict__ basep,
                                               const int* __restrict__ auxs, int ET) {
    int i = blockIdx.x * 256 + threadIdx.x;
    if (i < N_NODES) basep[i] += auxs[i >> 10];
    if (i == 0) basep[N_NODES] = ET;
}

// ------- scatter srcs into dst-sorted order (no atomics) ------------------
__global__ __launch_bounds__(256) void k_scatter(const int* __restrict__ ei, int E,
                                                 const int* __restrict__ basep,
                                                 const int* __restrict__ rank,
                                                 int* __restrict__ srcs) {
    int e = blockIdx.x * 256 + threadIdx.x;
    int ET = E + N_NODES;
    if (e >= ET) return;
    int s = (e < E) ? ei[e] : (e - E);
    int d = (e < E) ? ei[E + e] : (e - E);
    srcs[basep[d] + rank[e]] = s;
}

// ------- GEMM1 (MFMA) + fused att1 dots: h1b, as1, ad1 --------------------
// block tile 64x128, 4 waves in 2x2, KB=64 per step, 8 steps
__global__ __launch_bounds__(256) void k_gemm1(const float* __restrict__ x,
                                               const __bf16* __restrict__ Wp,
                                               const float* __restrict__ asrc1,
                                               const float* __restrict__ adst1,
                                               __bf16* __restrict__ h1b,
                                               float* __restrict__ as1,
                                               float* __restrict__ ad1) {
    __shared__ __align__(16) __bf16 As[64 * 64];    // [row][k], XOR-swizzled
    __shared__ __align__(16) __bf16 Bs[64 * 128];   // [kgrp][col][8k], col^kgrp swz
    const int t = threadIdx.x;
    const int l = t & 63;
    const int w = t >> 6;
    const int wr = (w >> 1) * 32, wc = (w & 1) * 64;
    const int n0 = blockIdx.x * 64;

    f32x4 acc[2][4];
    #pragma unroll
    for (int i = 0; i < 2; ++i)
        #pragma unroll
        for (int j = 0; j < 4; ++j) acc[i][j] = (f32x4){0.f, 0.f, 0.f, 0.f};

    const int arow = t >> 4;            // staging row base (0..15)
    const int ak4  = (t & 15) * 4;      // staging k offset (elements)

    for (int s = 0; s < 8; ++s) {
        const int k0 = s * 64;
        // --- stage A: x[n0..n0+64][k0..k0+64] f32 -> bf16, swizzled ---
        #pragma unroll
        for (int i = 0; i < 4; ++i) {
            int row = arow + i * 16;
            int grow = n0 + row;
            float4 f = {0.f, 0.f, 0.f, 0.f};
            if (grow < N_NODES)
                f = *(const float4*)(x + (size_t)grow * FIN + k0 + ak4);
            bf16x4 v = {(__bf16)f.x, (__bf16)f.y, (__bf16)f.z, (__bf16)f.w};
            int eo = (row * 64 + ak4) ^ ((row & 7) << 3);
            *(bf16x4*)(As + eo) = v;
        }
        // --- stage B: linear 16KB copy of packed Wp, col^kgrp swizzle ---
        const uint4* gb = (const uint4*)(Wp + k0 * 128);
        #pragma unroll
        for (int i = 0; i < 4; ++i) {
            int u = t + i * 256;                 // 16B unit: kgrp=u>>7, col=u&127
            uint4 d = gb[u];
            int u2 = u ^ ((u >> 7) & 3);
            *(uint4*)(Bs + u2 * 8) = d;
        }
        __syncthreads();
        // --- MFMA: 2 k-substeps x 2 m-frags x 4 n-frags ---
        #pragma unroll
        for (int ks = 0; ks < 2; ++ks) {
            bf16x8 af[2], bf[4];
            #pragma unroll
            for (int fm = 0; fm < 2; ++fm) {
                int row = wr + fm * 16 + (l & 15);
                int eo = (row * 64 + ks * 32 + (l >> 4) * 8) ^ ((row & 7) << 3);
                af[fm] = *(const bf16x8*)(As + eo);
            }
            #pragma unroll
            for (int fn = 0; fn < 4; ++fn) {
                int col = wc + fn * 16 + (l & 15);
                int kg = ks * 4 + (l >> 4);
                int u = (kg * 128 + col) ^ (kg & 3);
                bf[fn] = *(const bf16x8*)(Bs + u * 8);
            }
            #pragma unroll
            for (int fm = 0; fm < 2; ++fm)
                #pragma unroll
                for (int fn = 0; fn < 4; ++fn)
                    acc[fm][fn] = __builtin_amdgcn_mfma_f32_16x16x32_bf16(
                        af[fm], bf[fn], acc[fm][fn], 0, 0, 0);
        }
        __syncthreads();
    }
    // --- epilogue: C[row][col] -> bf16, row=(l>>4)*4+reg, col=l&15 ---
    #pragma unroll
    for (int fm = 0; fm < 2; ++fm) {
        #pragma unroll
        for (int reg = 0; reg < 4; ++reg) {
            int row = n0 + wr + fm * 16 + (l >> 4) * 4 + reg;
            if (row >= N_NODES) continue;
            #pragma unroll
            for (int fn = 0; fn < 4; ++fn) {
                int col = wc + fn * 16 + (l & 15);
                h1b[(size_t)row * D1 + col] = (__bf16)acc[fm][fn][reg];
            }
        }
    }
    // --- fused att1: per (fm,reg,fn) reduce C[row][head-cols] . a vectors ---
    const int c16 = l & 15;
    float av[4], dv[4];
    #pragma unroll
    for (int fn = 0; fn < 4; ++fn) {
        int head = (wc >> 4) + fn;
        av[fn] = asrc1[head * 16 + c16];
        dv[fn] = adst1[head * 16 + c16];
    }
    #pragma unroll
    for (int fm = 0; fm < 2; ++fm) {
        #pragma unroll
        for (int reg = 0; reg < 4; ++reg) {
            #pragma unroll
            for (int fn = 0; fn < 4; ++fn) {
                float vs = acc[fm][fn][reg] * av[fn];
                float vd = acc[fm][fn][reg] * dv[fn];
                #pragma unroll
                for (int mk = 1; mk <= 8; mk <<= 1) {
                    vs += __shfl_xor(vs, mk, 64);
                    vd += __shfl_xor(vd, mk, 64);
                }
                if (c16 == 0) {
                    int row = n0 + wr + fm * 16 + (l >> 4) * 4 + reg;
                    if (row < N_NODES) {
                        int head = (wc >> 4) + fn;
                        as1[(size_t)row * 8 + head] = vs;
                        ad1[(size_t)row * 8 + head] = vd;
                    }
                }
            }
        }
    }
}

// ------- aggregation layer 1: fused edge-exp + gather, wave/node ----------
// phase A: lane j computes edge j's 8 ee values -> LDS; phase B: 2 edges/iter
__global__ __launch_bounds__(256) void k_agg1(const int* __restrict__ basep,
                                              const int* __restrict__ srcs,
                                              const float* __restrict__ as1,
                                              const float* __restrict__ ad1,
                                              const __bf16* __restrict__ h1b,
                                              const float* __restrict__ b1,
                                              __bf16* __restrict__ r1b) {
    __shared__ float elds[4][512];
    const int w = threadIdx.x >> 6;
    const int l = threadIdx.x & 63;
    const int half = l >> 5;                   // which edge of the pair
    const int c4 = (l & 31) * 4;               // 4 channels per lane
    const int h = c4 >> 4;                     // head of this channel group
    const int n = blockIdx.x * 4 + w;          // 12500 blocks exactly
    const int p0 = basep[n], p1 = basep[n + 1];
    const int m = p1 - p0;
    float adv[8];
    #pragma unroll
    for (int i = 0; i < 8; ++i) adv[i] = ad1[(size_t)n * 8 + i];
    float a0 = 0.f, a1 = 0.f, a2 = 0.f, a3 = 0.f, se = 0.f;
    for (int base = 0; base < m; base += 64) {
        const int cm = min(64, m - base);
        asm volatile("s_waitcnt lgkmcnt(0)" ::: "memory");   // prior reads done
        int my_s = 0;
        if (l < cm) {
            my_s = srcs[p0 + base + l];
            const float4* ap = (const float4*)(as1 + (size_t)my_s * 8);
            float4 A0 = ap[0], A1 = ap[1];
            float uu[8] = {A0.x + adv[0], A0.y + adv[1], A0.z + adv[2], A0.w + adv[3],
                           A1.x + adv[4], A1.y + adv[5], A1.z + adv[6], A1.w + adv[7]};
            float ee[8];
            #pragma unroll
            for (int i = 0; i < 8; ++i) {
                float u = uu[i];
                u = (u > 0.f) ? u : 0.2f * u;
                ee[i] = __expf(u);
            }
            *(float4*)(&elds[w][l * 8])     = make_float4(ee[0], ee[1], ee[2], ee[3]);
            *(float4*)(&elds[w][l * 8 + 4]) = make_float4(ee[4], ee[5], ee[6], ee[7]);
        }
        asm volatile("s_waitcnt lgkmcnt(0)" ::: "memory");   // writes visible
        #pragma unroll 2
        for (int j2 = 0; j2 < cm; j2 += 2) {
            int j = j2 + half;
            bool ok = j < cm;
            int jj = ok ? j : 0;
            int s = __shfl(my_s, jj, 64);
            float ee = elds[w][jj * 8 + h];
            if (!ok) ee = 0.f;
            se += ee;
            bf16x4 hv = *(const bf16x4*)(h1b + (size_t)s * D1 + c4);
            a0 += ee * (float)hv.x;
            a1 += ee * (float)hv.y;
            a2 += ee * (float)hv.z;
            a3 += ee * (float)hv.w;
        }
    }
    a0 += __shfl_xor(a0, 32, 64);
    a1 += __shfl_xor(a1, 32, 64);
    a2 += __shfl_xor(a2, 32, 64);
    a3 += __shfl_xor(a3, 32, 64);
    se += __shfl_xor(se, 32, 64);
    if (half == 0) {
        float inv = 1.f / (se + 1e-16f);
        bf16x4 r = {(__bf16)fmaxf(a0 * inv + b1[c4], 0.f),
                    (__bf16)fmaxf(a1 * inv + b1[c4 + 1], 0.f),
                    (__bf16)fmaxf(a2 * inv + b1[c4 + 2], 0.f),
                    (__bf16)fmaxf(a3 * inv + b1[c4 + 3], 0.f)};
        *(bf16x4*)(r1b + (size_t)n * D1 + c4) = r;
    }
}

// ------- GEMM2 (MFMA) + fused att2 dots: h2b, as2, ad2 --------------------
// block tile 128x64, K=128 staged once, 4 waves each 32 rows x 64 cols
__global__ __launch_bounds__(256) void k_gemm2(const __bf16* __restrict__ r1b,
                                               const __bf16* __restrict__ Wp2,
                                               const float* __restrict__ av2,
                                               const float* __restrict__ dv2,
                                               __bf16* __restrict__ h2b,
                                               float* __restrict__ as2,
                                               float* __restrict__ ad2) {
    __shared__ __align__(16) __bf16 As[128 * 128];  // 32KB, XOR-swizzled
    __shared__ __align__(16) __bf16 Bs[128 * 64];   // 16KB, packed+swizzled
    const int t = threadIdx.x;
    const int l = t & 63;
    const int w = t >> 6;
    const int wr = w * 32;
    const int n0 = blockIdx.x * 128;

    // stage B: 1024 x 16B chunks (kg = u>>6, col = u&63)
    const uint4* gb = (const uint4*)Wp2;
    #pragma unroll
    for (int i = 0; i < 4; ++i) {
        int u = t + i * 256;
        uint4 d = gb[u];
        int u2 = u ^ ((u >> 6) & 3);
        *(uint4*)(Bs + u2 * 8) = d;
    }
    // stage A: 2048 x 16B chunks (row = u>>4, koff = (u&15)*8)
    #pragma unroll
    for (int i = 0; i < 8; ++i) {
        int u = t + i * 256;
        int row = u >> 4, koff = (u & 15) * 8;
        bf16x8 v = {};
        if (n0 + row < N_NODES)
            v = *(const bf16x8*)(r1b + (size_t)(n0 + row) * D1 + koff);
        int eo = (row * 128 + koff) ^ ((row & 7) << 3);
        *(bf16x8*)(As + eo) = v;
    }
    __syncthreads();

    f32x4 acc[2][4];
    #pragma unroll
    for (int i = 0; i < 2; ++i)
        #pragma unroll
        for (int j = 0; j < 4; ++j) acc[i][j] = (f32x4){0.f, 0.f, 0.f, 0.f};

    #pragma unroll
    for (int ks = 0; ks < 4; ++ks) {
        bf16x8 af[2], bfr[4];
        #pragma unroll
        for (int fm = 0; fm < 2; ++fm) {
            int row = wr + fm * 16 + (l & 15);
            int eo = (row * 128 + ks * 32 + (l >> 4) * 8) ^ ((row & 7) << 3);
            af[fm] = *(const bf16x8*)(As + eo);
        }
        #pragma unroll
        for (int fn = 0; fn < 4; ++fn) {
            int col = fn * 16 + (l & 15);
            int kg = ks * 4 + (l >> 4);
            int u = (kg * 64 + col) ^ (kg & 3);
            bfr[fn] = *(const bf16x8*)(Bs + u * 8);
        }
        #pragma unroll
        for (int fm = 0; fm < 2; ++fm)
            #pragma unroll
            for (int fn = 0; fn < 4; ++fn)
                acc[fm][fn] = __builtin_amdgcn_mfma_f32_16x16x32_bf16(
                    af[fm], bfr[fn], acc[fm][fn], 0, 0, 0);
    }
    // epilogue: store bf16 h2
    #pragma unroll
    for (int fm = 0; fm < 2; ++fm) {
        #pragma unroll
        for (int reg = 0; reg < 4; ++reg) {
            int row = n0 + wr + fm * 16 + (l >> 4) * 4 + reg;
            if (row >= N_NODES) continue;
            #pragma unroll
            for (int fn = 0; fn < 4; ++fn) {
                int col = fn * 16 + (l & 15);
                h2b[(size_t)row * D2 + col] = (__bf16)acc[fm][fn][reg];
            }
        }
    }
    // fused att2: single head over all 64 cols
    const int c16 = l & 15;
    float av[4], dv[4];
    #pragma unroll
    for (int fn = 0; fn < 4; ++fn) {
        av[fn] = av2[fn * 16 + c16];
        dv[fn] = dv2[fn * 16 + c16];
    }
    #pragma unroll
    for (int fm = 0; fm < 2; ++fm) {
        #pragma unroll
        for (int reg = 0; reg < 4; ++reg) {
            float vs = 0.f, vd = 0.f;
            #pragma unroll
            for (int fn = 0; fn < 4; ++fn) {
                vs += acc[fm][fn][reg] * av[fn];
                vd += acc[fm][fn][reg] * dv[fn];
            }
            #pragma unroll
            for (int mk = 1; mk <= 8; mk <<= 1) {
                vs += __shfl_xor(vs, mk, 64);
                vd += __shfl_xor(vd, mk, 64);
            }
            if (c16 == 0) {
                int row = n0 + wr + fm * 16 + (l >> 4) * 4 + reg;
                if (row < N_NODES) { as2[row] = vs; ad2[row] = vd; }
            }
        }
    }
}

// ------- aggregation layer 2: fused edge-exp + gather + log_softmax -------
// phase A: lane j computes edge j's ee (reg only); phase B: 4 edges/iter
__global__ __launch_bounds__(256) void k_agg2(const int* __restrict__ basep,
                                              const int* __restrict__ srcs,
                                              const float* __restrict__ as2,
                                              const float* __restrict__ ad2,
                                              const __bf16* __restrict__ h2b,
                                              const float* __restrict__ b2,
                                              float* __restrict__ out) {
    const int w = threadIdx.x >> 6;
    const int l = threadIdx.x & 63;
    const int q = l >> 4;                      // edge slot within quad
    const int c4 = (l & 15) * 4;               // 4 channels per lane
    const int n = blockIdx.x * 4 + w;          // 12500 blocks exactly
    const int p0 = basep[n], p1 = basep[n + 1];
    const int m = p1 - p0;
    const float adn = ad2[n];
    float a0 = 0.f, a1 = 0.f, a2 = 0.f, a3 = 0.f, se = 0.f;
    for (int base = 0; base < m; base += 64) {
        const int cm = min(64, m - base);
        int my_s = 0; float my_e = 0.f;
        if (l < cm) {
            my_s = srcs[p0 + base + l];
            float u = as2[my_s] + adn;
            u = (u > 0.f) ? u : 0.2f * u;
            my_e = __expf(u);
        }
        #pragma unroll 2
        for (int j4 = 0; j4 < cm; j4 += 4) {
            int j = j4 + q;
            bool ok = j < cm;
            int jj = ok ? j : 0;
            int s = __shfl(my_s, jj, 64);
            float ee = __shfl(my_e, jj, 64);
            if (!ok) ee = 0.f;
            se += ee;
            bf16x4 hv = *(const bf16x4*)(h2b + (size_t)s * D2 + c4);
            a0 += ee * (float)hv.x;
            a1 += ee * (float)hv.y;
            a2 += ee * (float)hv.z;
            a3 += ee * (float)hv.w;
        }
    }
    #pragma unroll
    for (int mk = 16; mk <= 32; mk <<= 1) {
        a0 += __shfl_xor(a0, mk, 64);
        a1 += __shfl_xor(a1, mk, 64);
        a2 += __shfl_xor(a2, mk, 64);
        a3 += __shfl_xor(a3, mk, 64);
        se += __shfl_xor(se, mk, 64);
    }
    float inv = 1.f / (se + 1e-16f);
    float v0 = a0 * inv + b2[c4];
    float v1 = a1 * inv + b2[c4 + 1];
    float v2 = a2 * inv + b2[c4 + 2];
    float v3 = a3 * inv + b2[c4 + 3];
    // log_softmax over 64 channels (held by 16 lanes, duplicated in quads)
    float mx = fmaxf(fmaxf(v0, v1), fmaxf(v2, v3));
    #pragma unroll
    for (int mk = 1; mk <= 8; mk <<= 1) mx = fmaxf(mx, __shfl_xor(mx, mk, 64));
    float ex = __expf(v0 - mx) + __expf(v1 - mx) + __expf(v2 - mx) + __expf(v3 - mx);
    #pragma unroll
    for (int mk = 1; mk <= 8; mk <<= 1) ex += __shfl_xor(ex, mk, 64);
    float lse = mx + __logf(ex);
    if (q == 0) {
        float4 r = {v0 - lse, v1 - lse, v2 - lse, v3 - lse};
        *(float4*)(out + (size_t)n * D2 + c4) = r;
    }
}

extern "C" void kernel_launch(void* const* d_in, const int* in_sizes, int n_in,
                              void* d_out, int out_size, void* d_ws, size_t ws_size,
                              hipStream_t stream) {
    const float* x     = (const float*)d_in[0];
    const int*   ei    = (const int*)d_in[1];
    const float* W1    = (const float*)d_in[2];
    const float* asrc1 = (const float*)d_in[3];
    const float* adst1 = (const float*)d_in[4];
    const float* b1    = (const float*)d_in[5];
    const float* W2    = (const float*)d_in[6];
    const float* asrc2 = (const float*)d_in[7];
    const float* adst2 = (const float*)d_in[8];
    const float* b2    = (const float*)d_in[9];

    const int E  = in_sizes[1] / 2;   // 800000
    const int ET = E + N_NODES;       // 850000

    // ---- workspace layout ----
    __bf16* r1b = (__bf16*)d_ws;                        // N*128 bf16 (relu1)
    float* fw  = (float*)(r1b + (size_t)N_NODES * D1);
    float* as1  = fw;                                   // N*8
    float* ad1  = as1  + (size_t)N_NODES * H1;          // N*8
    float* as2  = ad1  + (size_t)N_NODES * H1;          // N
    float* ad2  = as2  + N_NODES;                       // N
    int* iw   = (int*)(ad2 + N_NODES);
    int* cnt  = iw;                                     // N
    int* basep= cnt  + N_NODES;                         // N+1
    int* aux  = basep + N_NODES + 1;                    // 64
    int* auxs = aux  + 64;                              // 64
    int* rank = auxs + 64;                              // ET
    int* srcs = rank + ET;                              // ET
    uintptr_t pa = ((uintptr_t)(srcs + ET) + 255) & ~(uintptr_t)255;
    __bf16* Wp   = (__bf16*)pa;                         // 512*128 bf16
    __bf16* Wp2  = Wp  + (size_t)FIN * D1;              // 128*64 bf16
    __bf16* h1b  = Wp2 + (size_t)D1 * D2;               // N*128 bf16
    __bf16* h2b  = h1b + (size_t)N_NODES * D1;          // N*64 bf16

    const int gE = (ET + 255) / 256;
    const int gN = (N_NODES + 255) / 256;

    k_prep   <<<FIN * D1 / 256, 256, 0, stream>>>(W1, W2, Wp, Wp2, cnt);
    k_hist   <<<gE, 256, 0, stream>>>(ei, E, cnt, rank);
    k_scan1  <<<NSCB, 256, 0, stream>>>(cnt, basep, aux);
    k_scan2  <<<1, 64, 0, stream>>>(aux, auxs);
    k_scan3  <<<gN, 256, 0, stream>>>(basep, auxs, ET);
    k_scatter<<<gE, 256, 0, stream>>>(ei, E, basep, rank, srcs);

    k_gemm1  <<<(N_NODES + 63) / 64, 256, 0, stream>>>(x, Wp, asrc1, adst1, h1b, as1, ad1);
    k_agg1   <<<N_NODES / 4, 256, 0, stream>>>(basep, srcs, as1, ad1, h1b, b1, r1b);
    k_gemm2  <<<(N_NODES + 127) / 128, 256, 0, stream>>>(r1b, Wp2, asrc2, adst2, h2b, as2, ad2);
    k_agg2   <<<N_NODES / 4, 256, 0, stream>>>(basep, srcs, as2, ad2, h2b, b2, (float*)d_out);
}